// Round 1
// baseline (1709.341 us; speedup 1.0000x reference)
//
#include <hip/hip_runtime.h>
#include <math.h>

#define TOK    8192
#define DMODEL 512
#define FDIM   2048
#define NH     8
#define DKH    64
#define SEQ    1024
#define BATCH  8
#define KCONV  31
#define LN_EPS 1e-5f

__device__ __forceinline__ float sigf(float x) { return 1.0f / (1.0f + expf(-x)); }

// ---------------- LayerNorm: one wave (64 lanes) per 512-wide row ----------
__global__ __launch_bounds__(256) void ln_kernel(const float* __restrict__ in,
                                                 const float* __restrict__ g,
                                                 const float* __restrict__ b,
                                                 float* __restrict__ out) {
  const int wave = threadIdx.x >> 6, lane = threadIdx.x & 63;
  const size_t row = (size_t)blockIdx.x * 4 + wave;
  const float* p = in + row * DMODEL + lane * 8;
  const float4 v0 = *(const float4*)p;
  const float4 v1 = *(const float4*)(p + 4);
  float s  = v0.x + v0.y + v0.z + v0.w + v1.x + v1.y + v1.z + v1.w;
  float ss = v0.x*v0.x + v0.y*v0.y + v0.z*v0.z + v0.w*v0.w
           + v1.x*v1.x + v1.y*v1.y + v1.z*v1.z + v1.w*v1.w;
#pragma unroll
  for (int m = 1; m < 64; m <<= 1) { s += __shfl_xor(s, m); ss += __shfl_xor(ss, m); }
  const float mean = s * (1.0f / DMODEL);
  const float var  = ss * (1.0f / DMODEL) - mean * mean;
  const float rstd = rsqrtf(var + LN_EPS);
  const float4 g0 = *(const float4*)(g + lane * 8);
  const float4 g1 = *(const float4*)(g + lane * 8 + 4);
  const float4 bb0 = *(const float4*)(b + lane * 8);
  const float4 bb1 = *(const float4*)(b + lane * 8 + 4);
  float4 o0, o1;
  o0.x = (v0.x - mean) * rstd * g0.x + bb0.x;
  o0.y = (v0.y - mean) * rstd * g0.y + bb0.y;
  o0.z = (v0.z - mean) * rstd * g0.z + bb0.z;
  o0.w = (v0.w - mean) * rstd * g0.w + bb0.w;
  o1.x = (v1.x - mean) * rstd * g1.x + bb1.x;
  o1.y = (v1.y - mean) * rstd * g1.y + bb1.y;
  o1.z = (v1.z - mean) * rstd * g1.z + bb1.z;
  o1.w = (v1.w - mean) * rstd * g1.w + bb1.w;
  float* q = out + row * DMODEL + lane * 8;
  *(float4*)q = o0;
  *(float4*)(q + 4) = o1;
}

// ---------------- fp32 tiled GEMM: C = act(A@B + bias) [*alpha + Res] -------
// A[M,K] row-major, B[K,N] row-major. BM=BN=128, BK=16, 256 thr, 8x8/thread.
// ACT: 0 none, 1 relu.  RES: out = Res + alpha*(...)
template <int ACT, bool RES>
__global__ __launch_bounds__(256) void gemm_f32(const float* __restrict__ A,
                                                const float* __restrict__ B,
                                                const float* __restrict__ bias,
                                                const float* __restrict__ Rp,
                                                float alpha,
                                                float* __restrict__ C,
                                                int M, int N, int K) {
  __shared__ float As[16][132];   // transposed: As[k][m]
  __shared__ float Bs[16][132];   // Bs[k][n]
  const int t = threadIdx.x;
  const int tx = t & 15, ty = t >> 4;
  const int m0 = blockIdx.y * 128, n0 = blockIdx.x * 128;

  float acc[8][8];
#pragma unroll
  for (int i = 0; i < 8; ++i)
#pragma unroll
    for (int j = 0; j < 8; ++j) acc[i][j] = 0.f;

  const int ar = t >> 2;         // 0..63
  const int ak = (t & 3) * 4;    // 0,4,8,12
  const int bk = t >> 4;         // 0..15
  const int bn = (t & 15) * 4;   // 0..60

  for (int k0 = 0; k0 < K; k0 += 16) {
    const float4 av0 = *(const float4*)&A[(size_t)(m0 + ar) * K + k0 + ak];
    const float4 av1 = *(const float4*)&A[(size_t)(m0 + ar + 64) * K + k0 + ak];
    const float4 bv0 = *(const float4*)&B[(size_t)(k0 + bk) * N + n0 + bn];
    const float4 bv1 = *(const float4*)&B[(size_t)(k0 + bk) * N + n0 + bn + 64];
    __syncthreads();
    As[ak + 0][ar] = av0.x; As[ak + 1][ar] = av0.y;
    As[ak + 2][ar] = av0.z; As[ak + 3][ar] = av0.w;
    As[ak + 0][ar + 64] = av1.x; As[ak + 1][ar + 64] = av1.y;
    As[ak + 2][ar + 64] = av1.z; As[ak + 3][ar + 64] = av1.w;
    *(float4*)&Bs[bk][bn] = bv0;
    *(float4*)&Bs[bk][bn + 64] = bv1;
    __syncthreads();
#pragma unroll
    for (int kk = 0; kk < 16; ++kk) {
      const float4 a0 = *(const float4*)&As[kk][ty * 4];
      const float4 a1 = *(const float4*)&As[kk][ty * 4 + 64];
      const float4 b0 = *(const float4*)&Bs[kk][tx * 4];
      const float4 b1 = *(const float4*)&Bs[kk][tx * 4 + 64];
      const float aa[8] = {a0.x, a0.y, a0.z, a0.w, a1.x, a1.y, a1.z, a1.w};
      const float bbv[8] = {b0.x, b0.y, b0.z, b0.w, b1.x, b1.y, b1.z, b1.w};
#pragma unroll
      for (int i = 0; i < 8; ++i)
#pragma unroll
        for (int j = 0; j < 8; ++j) acc[i][j] = fmaf(aa[i], bbv[j], acc[i][j]);
    }
  }

#pragma unroll
  for (int ib = 0; ib < 2; ++ib)
#pragma unroll
    for (int i = 0; i < 4; ++i) {
      const int row = m0 + ib * 64 + ty * 4 + i;
#pragma unroll
      for (int jb = 0; jb < 2; ++jb) {
        const int col = n0 + jb * 64 + tx * 4;
        float4 o;
        float vv[4];
#pragma unroll
        for (int j = 0; j < 4; ++j) {
          float v = acc[ib * 4 + i][jb * 4 + j] + bias[col + j];
          if (ACT == 1) v = fmaxf(v, 0.f);
          if (RES) v = Rp[(size_t)row * N + col + j] + alpha * v;
          vv[j] = v;
        }
        o.x = vv[0]; o.y = vv[1]; o.z = vv[2]; o.w = vv[3];
        *(float4*)&C[(size_t)row * N + col] = o;
      }
    }
}

// ---------------- flash attention, fp32, 64x64 tiles ------------------------
// grid: (SEQ/64, NH, BATCH), 256 threads. Q/K/V/O are [8192, 512], head h at
// column h*64.
__global__ __launch_bounds__(256) void attn_kernel(const float* __restrict__ Qm,
                                                   const float* __restrict__ Km,
                                                   const float* __restrict__ Vm,
                                                   float* __restrict__ Om) {
  __shared__ float Qs[64][68];   // [dk][row]
  __shared__ float Ks[64][68];   // [dk][key]
  __shared__ float Vs[64][68];   // [key][dk]
  __shared__ float Ps[64][68];   // [row][key]
  const int t = threadIdx.x;
  const int tx = t & 15, ty = t >> 4;
  const int qb = blockIdx.x, h = blockIdx.y, b = blockIdx.z;
  const size_t base = ((size_t)b * SEQ) * DMODEL + (size_t)h * DKH;

  {
    const int r = t >> 2, c = (t & 3) * 16;
    const float* qp = Qm + base + (size_t)(qb * 64 + r) * DMODEL + c;
#pragma unroll
    for (int i = 0; i < 4; ++i) {
      const float4 v = *(const float4*)(qp + i * 4);
      Qs[c + i * 4 + 0][r] = v.x; Qs[c + i * 4 + 1][r] = v.y;
      Qs[c + i * 4 + 2][r] = v.z; Qs[c + i * 4 + 3][r] = v.w;
    }
  }

  float mrun[4], lrun[4], o_[4][4];
#pragma unroll
  for (int i = 0; i < 4; ++i) {
    mrun[i] = -1e30f; lrun[i] = 0.f;
#pragma unroll
    for (int j = 0; j < 4; ++j) o_[i][j] = 0.f;
  }

  for (int kt = 0; kt < SEQ / 64; ++kt) {
    __syncthreads();
    {
      const int r = t >> 2, c = (t & 3) * 16;
      const float* kp = Km + base + (size_t)(kt * 64 + r) * DMODEL + c;
      const float* vp = Vm + base + (size_t)(kt * 64 + r) * DMODEL + c;
#pragma unroll
      for (int i = 0; i < 4; ++i) {
        const float4 kv = *(const float4*)(kp + i * 4);
        Ks[c + i * 4 + 0][r] = kv.x; Ks[c + i * 4 + 1][r] = kv.y;
        Ks[c + i * 4 + 2][r] = kv.z; Ks[c + i * 4 + 3][r] = kv.w;
        *(float4*)&Vs[r][c + i * 4] = *(const float4*)(vp + i * 4);
      }
    }
    __syncthreads();

    float s[4][4];
#pragma unroll
    for (int i = 0; i < 4; ++i)
#pragma unroll
      for (int j = 0; j < 4; ++j) s[i][j] = 0.f;

#pragma unroll 8
    for (int kk = 0; kk < 64; ++kk) {
      const float4 qv = *(const float4*)&Qs[kk][ty * 4];
      const float4 kv = *(const float4*)&Ks[kk][tx * 4];
      const float qa[4] = {qv.x, qv.y, qv.z, qv.w};
      const float ka[4] = {kv.x, kv.y, kv.z, kv.w};
#pragma unroll
      for (int i = 0; i < 4; ++i)
#pragma unroll
        for (int j = 0; j < 4; ++j) s[i][j] = fmaf(qa[i], ka[j], s[i][j]);
    }

#pragma unroll
    for (int i = 0; i < 4; ++i) {
#pragma unroll
      for (int j = 0; j < 4; ++j) s[i][j] *= 0.125f;  // 1/sqrt(64)
      float rmax = fmaxf(fmaxf(s[i][0], s[i][1]), fmaxf(s[i][2], s[i][3]));
      rmax = fmaxf(rmax, __shfl_xor(rmax, 1));
      rmax = fmaxf(rmax, __shfl_xor(rmax, 2));
      rmax = fmaxf(rmax, __shfl_xor(rmax, 4));
      rmax = fmaxf(rmax, __shfl_xor(rmax, 8));
      const float mn = fmaxf(mrun[i], rmax);
      const float cs = expf(mrun[i] - mn);
      const float p0 = expf(s[i][0] - mn);
      const float p1 = expf(s[i][1] - mn);
      const float p2 = expf(s[i][2] - mn);
      const float p3 = expf(s[i][3] - mn);
      float4 pv4; pv4.x = p0; pv4.y = p1; pv4.z = p2; pv4.w = p3;
      *(float4*)&Ps[ty * 4 + i][tx * 4] = pv4;
      float rs = p0 + p1 + p2 + p3;
      rs += __shfl_xor(rs, 1);
      rs += __shfl_xor(rs, 2);
      rs += __shfl_xor(rs, 4);
      rs += __shfl_xor(rs, 8);
      lrun[i] = lrun[i] * cs + rs;
      mrun[i] = mn;
      o_[i][0] *= cs; o_[i][1] *= cs; o_[i][2] *= cs; o_[i][3] *= cs;
    }

    // P @ V  (Ps rows for this ty-group are written by this same wave)
#pragma unroll 4
    for (int j0 = 0; j0 < 16; ++j0) {
      float pa[4][4];
#pragma unroll
      for (int i = 0; i < 4; ++i) {
        const float4 pv = *(const float4*)&Ps[ty * 4 + i][j0 * 4];
        pa[i][0] = pv.x; pa[i][1] = pv.y; pa[i][2] = pv.z; pa[i][3] = pv.w;
      }
#pragma unroll
      for (int jj = 0; jj < 4; ++jj) {
        const float4 vv = *(const float4*)&Vs[j0 * 4 + jj][tx * 4];
#pragma unroll
        for (int i = 0; i < 4; ++i) {
          o_[i][0] = fmaf(pa[i][jj], vv.x, o_[i][0]);
          o_[i][1] = fmaf(pa[i][jj], vv.y, o_[i][1]);
          o_[i][2] = fmaf(pa[i][jj], vv.z, o_[i][2]);
          o_[i][3] = fmaf(pa[i][jj], vv.w, o_[i][3]);
        }
      }
    }
  }

#pragma unroll
  for (int i = 0; i < 4; ++i) {
    const float inv = 1.0f / lrun[i];
    float4 ov;
    ov.x = o_[i][0] * inv; ov.y = o_[i][1] * inv;
    ov.z = o_[i][2] * inv; ov.w = o_[i][3] * inv;
    *(float4*)&Om[base + (size_t)(qb * 64 + ty * 4 + i) * DMODEL + tx * 4] = ov;
  }
}

// ---------------- GLU over channels: out = a[:512] * sigmoid(a[512:]) -------
__global__ __launch_bounds__(256) void glu_kernel(const float* __restrict__ in,
                                                  float* __restrict__ out) {
  const size_t gid = (size_t)blockIdx.x * 256 + threadIdx.x;  // TOK*128
  const size_t row = gid >> 7;
  const int c = (int)(gid & 127) * 4;
  const float* p = in + row * (2 * DMODEL);
  const float4 a = *(const float4*)(p + c);
  const float4 g = *(const float4*)(p + DMODEL + c);
  float4 o;
  o.x = a.x * sigf(g.x); o.y = a.y * sigf(g.y);
  o.z = a.z * sigf(g.z); o.w = a.w * sigf(g.w);
  *(float4*)&out[row * DMODEL + c] = o;
}

// ---------------- transpose dw conv weight (D,1,K) -> (K,D) -----------------
__global__ void transpose_w(const float* __restrict__ w, float* __restrict__ wT) {
  const int idx = blockIdx.x * 256 + threadIdx.x;  // 512*31 = 15872
  if (idx < DMODEL * KCONV) {
    const int d = idx / KCONV, k = idx % KCONV;
    wT[k * DMODEL + d] = w[idx];
  }
}

// ---------------- depthwise conv (K=31, same pad) + bias + BN + SiLU --------
__global__ __launch_bounds__(256) void dwconv_bn_silu(const float* __restrict__ in,
                                                      const float* __restrict__ wT,
                                                      const float* __restrict__ dwb,
                                                      const float* __restrict__ bng,
                                                      const float* __restrict__ bnb,
                                                      const float* __restrict__ bnm,
                                                      const float* __restrict__ bnv,
                                                      float* __restrict__ out) {
  const size_t gid = (size_t)blockIdx.x * 256 + threadIdx.x;  // BATCH*SEQ*128
  const int dc = (int)(gid & 127) * 4;
  const int s = (int)((gid >> 7) & (SEQ - 1));
  const int b = (int)(gid >> 17);
  const float* bp = in + (size_t)b * SEQ * DMODEL;
  float ax = 0.f, ay = 0.f, az = 0.f, aw = 0.f;
#pragma unroll
  for (int k = 0; k < KCONV; ++k) {
    const int ssi = s + k - (KCONV / 2);
    if (ssi < 0 || ssi >= SEQ) continue;
    const float4 x = *(const float4*)(bp + (size_t)ssi * DMODEL + dc);
    const float4 w = *(const float4*)(wT + k * DMODEL + dc);
    ax = fmaf(x.x, w.x, ax); ay = fmaf(x.y, w.y, ay);
    az = fmaf(x.z, w.z, az); aw = fmaf(x.w, w.w, aw);
  }
  const float4 bi = *(const float4*)(dwb + dc);
  const float4 mm = *(const float4*)(bnm + dc);
  const float4 vv = *(const float4*)(bnv + dc);
  const float4 gg = *(const float4*)(bng + dc);
  const float4 b2 = *(const float4*)(bnb + dc);
  float v0 = ax + bi.x, v1 = ay + bi.y, v2 = az + bi.z, v3 = aw + bi.w;
  v0 = (v0 - mm.x) * rsqrtf(vv.x + LN_EPS) * gg.x + b2.x;
  v1 = (v1 - mm.y) * rsqrtf(vv.y + LN_EPS) * gg.y + b2.y;
  v2 = (v2 - mm.z) * rsqrtf(vv.z + LN_EPS) * gg.z + b2.z;
  v3 = (v3 - mm.w) * rsqrtf(vv.w + LN_EPS) * gg.w + b2.w;
  float4 o;
  o.x = v0 * sigf(v0); o.y = v1 * sigf(v1);
  o.z = v2 * sigf(v2); o.w = v3 * sigf(v3);
  *(float4*)&out[(((size_t)b * SEQ + s) * DMODEL) + dc] = o;
}

extern "C" void kernel_launch(void* const* d_in, const int* in_sizes, int n_in,
                              void* d_out, int out_size, void* d_ws, size_t ws_size,
                              hipStream_t stream) {
  const float* x    = (const float*)d_in[0];
  const float* n1g  = (const float*)d_in[1];
  const float* n1b  = (const float*)d_in[2];
  const float* n2g  = (const float*)d_in[3];
  const float* n2b  = (const float*)d_in[4];
  const float* n3g  = (const float*)d_in[5];
  const float* n3b  = (const float*)d_in[6];
  const float* n4g  = (const float*)d_in[7];
  const float* n4b  = (const float*)d_in[8];
  const float* clg  = (const float*)d_in[9];
  const float* clb  = (const float*)d_in[10];
  const float* f1w1 = (const float*)d_in[11];
  const float* f1b1 = (const float*)d_in[12];
  const float* f1w2 = (const float*)d_in[13];
  const float* f1b2 = (const float*)d_in[14];
  const float* f2w1 = (const float*)d_in[15];
  const float* f2b1 = (const float*)d_in[16];
  const float* f2w2 = (const float*)d_in[17];
  const float* f2b2 = (const float*)d_in[18];
  const float* wq   = (const float*)d_in[19];
  const float* bq   = (const float*)d_in[20];
  const float* wk   = (const float*)d_in[21];
  const float* bk   = (const float*)d_in[22];
  const float* wv   = (const float*)d_in[23];
  const float* bv   = (const float*)d_in[24];
  const float* wo   = (const float*)d_in[25];
  const float* bo   = (const float*)d_in[26];
  const float* pw1w = (const float*)d_in[27];
  const float* pw1b = (const float*)d_in[28];
  const float* dww  = (const float*)d_in[29];
  const float* dwb  = (const float*)d_in[30];
  const float* bng  = (const float*)d_in[31];
  const float* bnb  = (const float*)d_in[32];
  const float* bnm  = (const float*)d_in[33];
  const float* bnv  = (const float*)d_in[34];
  const float* pw2w = (const float*)d_in[35];
  const float* pw2b = (const float*)d_in[36];

  float* ws  = (float*)d_ws;
  float* A   = ws;                                  // TOK*FDIM  (64 MB)
  float* Bf  = A  + (size_t)TOK * FDIM;             // TOK*DMODEL
  float* Qb  = Bf + (size_t)TOK * DMODEL;
  float* Kb  = Qb + (size_t)TOK * DMODEL;
  float* Vb  = Kb + (size_t)TOK * DMODEL;
  float* WT  = Vb + (size_t)TOK * DMODEL;           // KCONV*DMODEL
  float* out = (float*)d_out;

  const dim3 blk(256);
  const dim3 gLN(TOK / 4);
  const dim3 gGemmF(FDIM / 128, TOK / 128);     // N=2048
  const dim3 gGemmD(DMODEL / 128, TOK / 128);   // N=512
  const dim3 gGemm2D(2 * DMODEL / 128, TOK / 128); // N=1024
  const dim3 gAttn(SEQ / 64, NH, BATCH);
  const dim3 gElem(TOK * 128 / 256);

  // conv weight transpose (tiny)
  transpose_w<<<62, blk, 0, stream>>>(dww, WT);

  // ---- FF1 half-step ----
  ln_kernel<<<gLN, blk, 0, stream>>>(x, n1g, n1b, Bf);
  gemm_f32<1, false><<<gGemmF, blk, 0, stream>>>(Bf, f1w1, f1b1, nullptr, 0.f, A, TOK, FDIM, DMODEL);
  gemm_f32<0, true ><<<gGemmD, blk, 0, stream>>>(A, f1w2, f1b2, x, 0.5f, out, TOK, DMODEL, FDIM);

  // ---- MHSA ----
  ln_kernel<<<gLN, blk, 0, stream>>>(out, n2g, n2b, Bf);
  gemm_f32<0, false><<<gGemmD, blk, 0, stream>>>(Bf, wq, bq, nullptr, 0.f, Qb, TOK, DMODEL, DMODEL);
  gemm_f32<0, false><<<gGemmD, blk, 0, stream>>>(Bf, wk, bk, nullptr, 0.f, Kb, TOK, DMODEL, DMODEL);
  gemm_f32<0, false><<<gGemmD, blk, 0, stream>>>(Bf, wv, bv, nullptr, 0.f, Vb, TOK, DMODEL, DMODEL);
  attn_kernel<<<gAttn, blk, 0, stream>>>(Qb, Kb, Vb, Bf);
  gemm_f32<0, true ><<<gGemmD, blk, 0, stream>>>(Bf, wo, bo, out, 1.0f, out, TOK, DMODEL, DMODEL);

  // ---- conv module ----
  ln_kernel<<<gLN, blk, 0, stream>>>(out, n3g, n3b, Qb);
  ln_kernel<<<gLN, blk, 0, stream>>>(Qb, clg, clb, Qb);
  gemm_f32<0, false><<<gGemm2D, blk, 0, stream>>>(Qb, pw1w, pw1b, nullptr, 0.f, A, TOK, 2 * DMODEL, DMODEL);
  glu_kernel<<<gElem, blk, 0, stream>>>(A, Bf);
  dwconv_bn_silu<<<gElem, blk, 0, stream>>>(Bf, WT, dwb, bng, bnb, bnm, bnv, Kb);
  gemm_f32<0, true ><<<gGemmD, blk, 0, stream>>>(Kb, pw2w, pw2b, out, 1.0f, out, TOK, DMODEL, DMODEL);

  // ---- FF2 half-step ----
  ln_kernel<<<gLN, blk, 0, stream>>>(out, n4g, n4b, Bf);
  gemm_f32<1, false><<<gGemmF, blk, 0, stream>>>(Bf, f2w1, f2b1, nullptr, 0.f, A, TOK, FDIM, DMODEL);
  gemm_f32<0, true ><<<gGemmD, blk, 0, stream>>>(A, f2w2, f2b2, out, 0.5f, out, TOK, DMODEL, FDIM);
}

// Round 2
// 659.220 us; speedup vs baseline: 2.5930x; 2.5930x over previous
//
#include <hip/hip_runtime.h>
#include <math.h>

#define TOK    8192
#define DMODEL 512
#define FDIM   2048
#define NH     8
#define DKH    64
#define SEQ    1024
#define BATCH  8
#define KCONV  31
#define LN_EPS 1e-5f

typedef __attribute__((ext_vector_type(8))) short bf16x8;
typedef __attribute__((ext_vector_type(4))) float f32x4;
typedef unsigned short ushort_t;

__device__ __forceinline__ float sigf(float x) { return 1.0f / (1.0f + expf(-x)); }

__device__ __forceinline__ unsigned short f2bf(float f) {
  unsigned u = __float_as_uint(f);
  u = u + 0x7fffu + ((u >> 16) & 1u);   // RNE
  return (unsigned short)(u >> 16);
}
__device__ __forceinline__ unsigned pk2(float a, float b) {
  return (unsigned)f2bf(a) | ((unsigned)f2bf(b) << 16);
}

// ---------------- weight cast+transpose: [K,N] f32 -> [N,K] bf16 ------------
__global__ __launch_bounds__(256) void wcast_t(const float* __restrict__ w,
                                               ushort_t* __restrict__ wt,
                                               int Kd, int Nd) {
  __shared__ float tile[32][33];
  const int bx = blockIdx.x * 32, by = blockIdx.y * 32;
  const int tx = threadIdx.x, ty = threadIdx.y;  // 32 x 8
#pragma unroll
  for (int i = 0; i < 32; i += 8)
    tile[ty + i][tx] = w[(size_t)(by + ty + i) * Nd + bx + tx];
  __syncthreads();
#pragma unroll
  for (int i = 0; i < 32; i += 8)
    wt[(size_t)(bx + ty + i) * Kd + by + tx] = f2bf(tile[tx][ty + i]);
}

// ---------------- LayerNorm: one wave per 512-wide row ----------------------
template <bool OBF>
__global__ __launch_bounds__(256) void ln_kernel(const float* __restrict__ in,
                                                 const float* __restrict__ g,
                                                 const float* __restrict__ b,
                                                 void* __restrict__ outp) {
  const int wave = threadIdx.x >> 6, lane = threadIdx.x & 63;
  const size_t row = (size_t)blockIdx.x * 4 + wave;
  const float* p = in + row * DMODEL + lane * 8;
  const float4 v0 = *(const float4*)p;
  const float4 v1 = *(const float4*)(p + 4);
  float s  = v0.x + v0.y + v0.z + v0.w + v1.x + v1.y + v1.z + v1.w;
  float ss = v0.x*v0.x + v0.y*v0.y + v0.z*v0.z + v0.w*v0.w
           + v1.x*v1.x + v1.y*v1.y + v1.z*v1.z + v1.w*v1.w;
#pragma unroll
  for (int m = 1; m < 64; m <<= 1) { s += __shfl_xor(s, m); ss += __shfl_xor(ss, m); }
  const float mean = s * (1.0f / DMODEL);
  const float var  = ss * (1.0f / DMODEL) - mean * mean;
  const float rstd = rsqrtf(var + LN_EPS);
  const float4 g0 = *(const float4*)(g + lane * 8);
  const float4 g1 = *(const float4*)(g + lane * 8 + 4);
  const float4 bb0 = *(const float4*)(b + lane * 8);
  const float4 bb1 = *(const float4*)(b + lane * 8 + 4);
  float o[8];
  o[0] = (v0.x - mean) * rstd * g0.x + bb0.x;
  o[1] = (v0.y - mean) * rstd * g0.y + bb0.y;
  o[2] = (v0.z - mean) * rstd * g0.z + bb0.z;
  o[3] = (v0.w - mean) * rstd * g0.w + bb0.w;
  o[4] = (v1.x - mean) * rstd * g1.x + bb1.x;
  o[5] = (v1.y - mean) * rstd * g1.y + bb1.y;
  o[6] = (v1.z - mean) * rstd * g1.z + bb1.z;
  o[7] = (v1.w - mean) * rstd * g1.w + bb1.w;
  if (OBF) {
    uint4 pkv;
    pkv.x = pk2(o[0], o[1]); pkv.y = pk2(o[2], o[3]);
    pkv.z = pk2(o[4], o[5]); pkv.w = pk2(o[6], o[7]);
    *(uint4*)((ushort_t*)outp + row * DMODEL + lane * 8) = pkv;
  } else {
    float4 a, c;
    a.x = o[0]; a.y = o[1]; a.z = o[2]; a.w = o[3];
    c.x = o[4]; c.y = o[5]; c.z = o[6]; c.w = o[7];
    float* q = (float*)outp + row * DMODEL + lane * 8;
    *(float4*)q = a;
    *(float4*)(q + 4) = c;
  }
}

// ---------------- bf16 MFMA GEMM (m97 structure) ----------------------------
// A [M,K] bf16 row-major; Bt [N,K] bf16 row-major (i.e. B transposed).
// C = act(A@B + bias); RES: C = Rp + alpha*C.  OBF: write bf16 else fp32.
// 128x128 tile, BK=64, 256 threads (4 waves, 2x2), 16x16x32 MFMA.
template <int ACT, bool RES, bool OBF>
__global__ __launch_bounds__(256) void gemm_bf16(const ushort_t* __restrict__ A,
                                                 const ushort_t* __restrict__ Bt,
                                                 const float* __restrict__ bias,
                                                 const float* __restrict__ Rp,
                                                 float alpha,
                                                 void* __restrict__ Cout,
                                                 int M, int N, int K) {
  __shared__ ushort_t Al[128 * 64];
  __shared__ ushort_t Bl[128 * 64];
  const int t = threadIdx.x;
  const int lane = t & 63;
  const int wid = t >> 6;
  const int wr = wid >> 1, wc = wid & 1;
  const int m0 = blockIdx.y * 128, n0 = blockIdx.x * 128;

  f32x4 acc[4][4];
#pragma unroll
  for (int m = 0; m < 4; ++m)
#pragma unroll
    for (int n = 0; n < 4; ++n) acc[m][n] = (f32x4){0.f, 0.f, 0.f, 0.f};

  // staging: 4 iters x 256 thr x 16B each for A and B tiles (16 KB each)
  const int srow = t >> 3;          // 0..31
  const int scol = (t & 7) * 8;     // k element offset
  const ushort_t* Ag = A + (size_t)(m0 + srow) * K + scol;
  const ushort_t* Bg = Bt + (size_t)(n0 + srow) * K + scol;

  for (int k0 = 0; k0 < K; k0 += 64) {
    __syncthreads();
#pragma unroll
    for (int i = 0; i < 4; ++i) {
      __builtin_amdgcn_global_load_lds(
          (const __attribute__((address_space(1))) unsigned*)(Ag + (size_t)i * 32 * K + k0),
          (__attribute__((address_space(3))) unsigned*)(Al + ((size_t)i * 256 + t) * 8),
          16, 0, 0);
    }
#pragma unroll
    for (int i = 0; i < 4; ++i) {
      __builtin_amdgcn_global_load_lds(
          (const __attribute__((address_space(1))) unsigned*)(Bg + (size_t)i * 32 * K + k0),
          (__attribute__((address_space(3))) unsigned*)(Bl + ((size_t)i * 256 + t) * 8),
          16, 0, 0);
    }
    __syncthreads();

#pragma unroll
    for (int ks = 0; ks < 2; ++ks) {
      const int kk = ks * 32 + (lane >> 4) * 8;
      bf16x8 af[4], bfv[4];
#pragma unroll
      for (int m = 0; m < 4; ++m)
        af[m] = *(const bf16x8*)(Al + (wr * 64 + m * 16 + (lane & 15)) * 64 + kk);
#pragma unroll
      for (int n = 0; n < 4; ++n)
        bfv[n] = *(const bf16x8*)(Bl + (wc * 64 + n * 16 + (lane & 15)) * 64 + kk);
#pragma unroll
      for (int m = 0; m < 4; ++m)
#pragma unroll
        for (int n = 0; n < 4; ++n)
          acc[m][n] = __builtin_amdgcn_mfma_f32_16x16x32_bf16(af[m], bfv[n], acc[m][n], 0, 0, 0);
    }
  }

  // epilogue: C/D layout col=lane&15, row=(lane>>4)*4+j
#pragma unroll
  for (int m = 0; m < 4; ++m) {
    const int row_b = m0 + wr * 64 + m * 16 + (lane >> 4) * 4;
#pragma unroll
    for (int n = 0; n < 4; ++n) {
      const int col = n0 + wc * 64 + n * 16 + (lane & 15);
      const float bv = bias[col];
#pragma unroll
      for (int j = 0; j < 4; ++j) {
        float v = acc[m][n][j] + bv;
        if (ACT == 1) v = fmaxf(v, 0.f);
        const size_t idx = (size_t)(row_b + j) * N + col;
        if (RES) v = Rp[idx] + alpha * v;
        if (OBF) ((ushort_t*)Cout)[idx] = f2bf(v);
        else     ((float*)Cout)[idx] = v;
      }
    }
  }
}

// ---------------- flash attention, fp32, 64x64 tiles, bf16 output ----------
__global__ __launch_bounds__(256) void attn_kernel(const float* __restrict__ Qm,
                                                   const float* __restrict__ Km,
                                                   const float* __restrict__ Vm,
                                                   ushort_t* __restrict__ Om) {
  __shared__ float Qs[64][68];
  __shared__ float Ks[64][68];
  __shared__ float Vs[64][68];
  __shared__ float Ps[64][68];
  const int t = threadIdx.x;
  const int tx = t & 15, ty = t >> 4;
  const int qb = blockIdx.x, h = blockIdx.y, b = blockIdx.z;
  const size_t base = ((size_t)b * SEQ) * DMODEL + (size_t)h * DKH;

  {
    const int r = t >> 2, c = (t & 3) * 16;
    const float* qp = Qm + base + (size_t)(qb * 64 + r) * DMODEL + c;
#pragma unroll
    for (int i = 0; i < 4; ++i) {
      const float4 v = *(const float4*)(qp + i * 4);
      Qs[c + i * 4 + 0][r] = v.x; Qs[c + i * 4 + 1][r] = v.y;
      Qs[c + i * 4 + 2][r] = v.z; Qs[c + i * 4 + 3][r] = v.w;
    }
  }

  float mrun[4], lrun[4], o_[4][4];
#pragma unroll
  for (int i = 0; i < 4; ++i) {
    mrun[i] = -1e30f; lrun[i] = 0.f;
#pragma unroll
    for (int j = 0; j < 4; ++j) o_[i][j] = 0.f;
  }

  for (int kt = 0; kt < SEQ / 64; ++kt) {
    __syncthreads();
    {
      const int r = t >> 2, c = (t & 3) * 16;
      const float* kp = Km + base + (size_t)(kt * 64 + r) * DMODEL + c;
      const float* vp = Vm + base + (size_t)(kt * 64 + r) * DMODEL + c;
#pragma unroll
      for (int i = 0; i < 4; ++i) {
        const float4 kv = *(const float4*)(kp + i * 4);
        Ks[c + i * 4 + 0][r] = kv.x; Ks[c + i * 4 + 1][r] = kv.y;
        Ks[c + i * 4 + 2][r] = kv.z; Ks[c + i * 4 + 3][r] = kv.w;
        *(float4*)&Vs[r][c + i * 4] = *(const float4*)(vp + i * 4);
      }
    }
    __syncthreads();

    float s[4][4];
#pragma unroll
    for (int i = 0; i < 4; ++i)
#pragma unroll
      for (int j = 0; j < 4; ++j) s[i][j] = 0.f;

#pragma unroll 8
    for (int kk = 0; kk < 64; ++kk) {
      const float4 qv = *(const float4*)&Qs[kk][ty * 4];
      const float4 kv = *(const float4*)&Ks[kk][tx * 4];
      const float qa[4] = {qv.x, qv.y, qv.z, qv.w};
      const float ka[4] = {kv.x, kv.y, kv.z, kv.w};
#pragma unroll
      for (int i = 0; i < 4; ++i)
#pragma unroll
        for (int j = 0; j < 4; ++j) s[i][j] = fmaf(qa[i], ka[j], s[i][j]);
    }

#pragma unroll
    for (int i = 0; i < 4; ++i) {
#pragma unroll
      for (int j = 0; j < 4; ++j) s[i][j] *= 0.125f;
      float rmax = fmaxf(fmaxf(s[i][0], s[i][1]), fmaxf(s[i][2], s[i][3]));
      rmax = fmaxf(rmax, __shfl_xor(rmax, 1));
      rmax = fmaxf(rmax, __shfl_xor(rmax, 2));
      rmax = fmaxf(rmax, __shfl_xor(rmax, 4));
      rmax = fmaxf(rmax, __shfl_xor(rmax, 8));
      const float mn = fmaxf(mrun[i], rmax);
      const float cs = expf(mrun[i] - mn);
      const float p0 = expf(s[i][0] - mn);
      const float p1 = expf(s[i][1] - mn);
      const float p2 = expf(s[i][2] - mn);
      const float p3 = expf(s[i][3] - mn);
      float4 pv4; pv4.x = p0; pv4.y = p1; pv4.z = p2; pv4.w = p3;
      *(float4*)&Ps[ty * 4 + i][tx * 4] = pv4;
      float rs = p0 + p1 + p2 + p3;
      rs += __shfl_xor(rs, 1);
      rs += __shfl_xor(rs, 2);
      rs += __shfl_xor(rs, 4);
      rs += __shfl_xor(rs, 8);
      lrun[i] = lrun[i] * cs + rs;
      mrun[i] = mn;
      o_[i][0] *= cs; o_[i][1] *= cs; o_[i][2] *= cs; o_[i][3] *= cs;
    }

#pragma unroll 4
    for (int j0 = 0; j0 < 16; ++j0) {
      float pa[4][4];
#pragma unroll
      for (int i = 0; i < 4; ++i) {
        const float4 pv = *(const float4*)&Ps[ty * 4 + i][j0 * 4];
        pa[i][0] = pv.x; pa[i][1] = pv.y; pa[i][2] = pv.z; pa[i][3] = pv.w;
      }
#pragma unroll
      for (int jj = 0; jj < 4; ++jj) {
        const float4 vv = *(const float4*)&Vs[j0 * 4 + jj][tx * 4];
#pragma unroll
        for (int i = 0; i < 4; ++i) {
          o_[i][0] = fmaf(pa[i][jj], vv.x, o_[i][0]);
          o_[i][1] = fmaf(pa[i][jj], vv.y, o_[i][1]);
          o_[i][2] = fmaf(pa[i][jj], vv.z, o_[i][2]);
          o_[i][3] = fmaf(pa[i][jj], vv.w, o_[i][3]);
        }
      }
    }
  }

#pragma unroll
  for (int i = 0; i < 4; ++i) {
    const float inv = 1.0f / lrun[i];
    uint2 ov;
    ov.x = pk2(o_[i][0] * inv, o_[i][1] * inv);
    ov.y = pk2(o_[i][2] * inv, o_[i][3] * inv);
    *(uint2*)&Om[base + (size_t)(qb * 64 + ty * 4 + i) * DMODEL + tx * 4] = ov;
  }
}

// ---------------- GLU over channels -----------------------------------------
__global__ __launch_bounds__(256) void glu_kernel(const float* __restrict__ in,
                                                  float* __restrict__ out) {
  const size_t gid = (size_t)blockIdx.x * 256 + threadIdx.x;
  const size_t row = gid >> 7;
  const int c = (int)(gid & 127) * 4;
  const float* p = in + row * (2 * DMODEL);
  const float4 a = *(const float4*)(p + c);
  const float4 g = *(const float4*)(p + DMODEL + c);
  float4 o;
  o.x = a.x * sigf(g.x); o.y = a.y * sigf(g.y);
  o.z = a.z * sigf(g.z); o.w = a.w * sigf(g.w);
  *(float4*)&out[row * DMODEL + c] = o;
}

// ---------------- transpose dw conv weight (D,1,K) -> (K,D) -----------------
__global__ void transpose_w(const float* __restrict__ w, float* __restrict__ wT) {
  const int idx = blockIdx.x * 256 + threadIdx.x;
  if (idx < DMODEL * KCONV) {
    const int d = idx / KCONV, k = idx % KCONV;
    wT[k * DMODEL + d] = w[idx];
  }
}

// ---------------- depthwise conv + bias + BN + SiLU, bf16 out ---------------
__global__ __launch_bounds__(256) void dwconv_bn_silu(const float* __restrict__ in,
                                                      const float* __restrict__ wT,
                                                      const float* __restrict__ dwb,
                                                      const float* __restrict__ bng,
                                                      const float* __restrict__ bnb,
                                                      const float* __restrict__ bnm,
                                                      const float* __restrict__ bnv,
                                                      ushort_t* __restrict__ out) {
  const size_t gid = (size_t)blockIdx.x * 256 + threadIdx.x;
  const int dc = (int)(gid & 127) * 4;
  const int s = (int)((gid >> 7) & (SEQ - 1));
  const int b = (int)(gid >> 17);
  const float* bp = in + (size_t)b * SEQ * DMODEL;
  float ax = 0.f, ay = 0.f, az = 0.f, aw = 0.f;
#pragma unroll
  for (int k = 0; k < KCONV; ++k) {
    const int ssi = s + k - (KCONV / 2);
    if (ssi < 0 || ssi >= SEQ) continue;
    const float4 x = *(const float4*)(bp + (size_t)ssi * DMODEL + dc);
    const float4 w = *(const float4*)(wT + k * DMODEL + dc);
    ax = fmaf(x.x, w.x, ax); ay = fmaf(x.y, w.y, ay);
    az = fmaf(x.z, w.z, az); aw = fmaf(x.w, w.w, aw);
  }
  const float4 bi = *(const float4*)(dwb + dc);
  const float4 mm = *(const float4*)(bnm + dc);
  const float4 vv = *(const float4*)(bnv + dc);
  const float4 gg = *(const float4*)(bng + dc);
  const float4 b2 = *(const float4*)(bnb + dc);
  float v0 = ax + bi.x, v1 = ay + bi.y, v2 = az + bi.z, v3 = aw + bi.w;
  v0 = (v0 - mm.x) * rsqrtf(vv.x + LN_EPS) * gg.x + b2.x;
  v1 = (v1 - mm.y) * rsqrtf(vv.y + LN_EPS) * gg.y + b2.y;
  v2 = (v2 - mm.z) * rsqrtf(vv.z + LN_EPS) * gg.z + b2.z;
  v3 = (v3 - mm.w) * rsqrtf(vv.w + LN_EPS) * gg.w + b2.w;
  v0 = v0 * sigf(v0); v1 = v1 * sigf(v1); v2 = v2 * sigf(v2); v3 = v3 * sigf(v3);
  uint2 o;
  o.x = pk2(v0, v1); o.y = pk2(v2, v3);
  *(uint2*)&out[(((size_t)b * SEQ + s) * DMODEL) + dc] = o;
}

extern "C" void kernel_launch(void* const* d_in, const int* in_sizes, int n_in,
                              void* d_out, int out_size, void* d_ws, size_t ws_size,
                              hipStream_t stream) {
  const float* x    = (const float*)d_in[0];
  const float* n1g  = (const float*)d_in[1];
  const float* n1b  = (const float*)d_in[2];
  const float* n2g  = (const float*)d_in[3];
  const float* n2b  = (const float*)d_in[4];
  const float* n3g  = (const float*)d_in[5];
  const float* n3b  = (const float*)d_in[6];
  const float* n4g  = (const float*)d_in[7];
  const float* n4b  = (const float*)d_in[8];
  const float* clg  = (const float*)d_in[9];
  const float* clb  = (const float*)d_in[10];
  const float* f1w1 = (const float*)d_in[11];
  const float* f1b1 = (const float*)d_in[12];
  const float* f1w2 = (const float*)d_in[13];
  const float* f1b2 = (const float*)d_in[14];
  const float* f2w1 = (const float*)d_in[15];
  const float* f2b1 = (const float*)d_in[16];
  const float* f2w2 = (const float*)d_in[17];
  const float* f2b2 = (const float*)d_in[18];
  const float* wq   = (const float*)d_in[19];
  const float* bq   = (const float*)d_in[20];
  const float* wk   = (const float*)d_in[21];
  const float* bk   = (const float*)d_in[22];
  const float* wv   = (const float*)d_in[23];
  const float* bv   = (const float*)d_in[24];
  const float* wo   = (const float*)d_in[25];
  const float* bo   = (const float*)d_in[26];
  const float* pw1w = (const float*)d_in[27];
  const float* pw1b = (const float*)d_in[28];
  const float* dww  = (const float*)d_in[29];
  const float* dwb  = (const float*)d_in[30];
  const float* bng  = (const float*)d_in[31];
  const float* bnb  = (const float*)d_in[32];
  const float* bnm  = (const float*)d_in[33];
  const float* bnv  = (const float*)d_in[34];
  const float* pw2w = (const float*)d_in[35];
  const float* pw2b = (const float*)d_in[36];

  char* wsb = (char*)d_ws;
  const size_t MB = 1ull << 20;
  // bf16 weights [N,K]
  ushort_t* Wbf    = (ushort_t*)(wsb + 0);            // 5.75M el = 11.5 MB
  ushort_t* f1w1T  = Wbf + 0;                         // [2048][512]
  ushort_t* f1w2T  = Wbf + (1ull << 20);              // [512][2048]
  ushort_t* f2w1T  = Wbf + (2ull << 20);
  ushort_t* f2w2T  = Wbf + (3ull << 20);
  ushort_t* wqT    = Wbf + (4ull << 20);              // [512][512]
  ushort_t* wkT    = Wbf + (4ull << 20) + (256ull << 10);
  ushort_t* wvT    = Wbf + (4ull << 20) + (512ull << 10);
  ushort_t* woT    = Wbf + (4ull << 20) + (768ull << 10);
  ushort_t* pw1T   = Wbf + (5ull << 20);              // [1024][512]
  ushort_t* pw2T   = Wbf + (5ull << 20) + (512ull << 10);
  float*    WTc    = (float*)(wsb + 12 * MB);         // conv dw weight [K][D]
  ushort_t* Lbf    = (ushort_t*)(wsb + 13 * MB);      // LN out bf16, 8 MB
  // R1 (32 MB): FF hidden bf16 [TOK,2048] / pw1 out f32 [TOK,1024]
  ushort_t* Hbf    = (ushort_t*)(wsb + 21 * MB);
  float*    P1f    = (float*)(wsb + 21 * MB);
  // R2 (48 MB): Q/K/V f32  OR  T1f/Gf f32
  float*    Qf     = (float*)(wsb + 53 * MB);
  float*    Kf     = (float*)(wsb + 69 * MB);
  float*    Vf     = (float*)(wsb + 85 * MB);
  float*    T1f    = (float*)(wsb + 53 * MB);
  float*    Gf     = (float*)(wsb + 69 * MB);
  // Obf (8 MB): attn out bf16, reused as conv-module bf16 out
  ushort_t* Obf    = (ushort_t*)(wsb + 101 * MB);
  ushort_t* Cbf    = Obf;
  float* out = (float*)d_out;

  const dim3 blk(256);
  const dim3 blkT(32, 8);
  const dim3 gLN(TOK / 4);
  const dim3 gGemmF(FDIM / 128, TOK / 128);
  const dim3 gGemmD(DMODEL / 128, TOK / 128);
  const dim3 gGemm2D(2 * DMODEL / 128, TOK / 128);
  const dim3 gAttn(SEQ / 64, NH, BATCH);
  const dim3 gElem(TOK * 128 / 256);

  // ---- weight preprocessing ----
  wcast_t<<<dim3(FDIM / 32, DMODEL / 32), blkT, 0, stream>>>(f1w1, f1w1T, DMODEL, FDIM);
  wcast_t<<<dim3(DMODEL / 32, FDIM / 32), blkT, 0, stream>>>(f1w2, f1w2T, FDIM, DMODEL);
  wcast_t<<<dim3(FDIM / 32, DMODEL / 32), blkT, 0, stream>>>(f2w1, f2w1T, DMODEL, FDIM);
  wcast_t<<<dim3(DMODEL / 32, FDIM / 32), blkT, 0, stream>>>(f2w2, f2w2T, FDIM, DMODEL);
  wcast_t<<<dim3(DMODEL / 32, DMODEL / 32), blkT, 0, stream>>>(wq, wqT, DMODEL, DMODEL);
  wcast_t<<<dim3(DMODEL / 32, DMODEL / 32), blkT, 0, stream>>>(wk, wkT, DMODEL, DMODEL);
  wcast_t<<<dim3(DMODEL / 32, DMODEL / 32), blkT, 0, stream>>>(wv, wvT, DMODEL, DMODEL);
  wcast_t<<<dim3(DMODEL / 32, DMODEL / 32), blkT, 0, stream>>>(wo, woT, DMODEL, DMODEL);
  wcast_t<<<dim3(2 * DMODEL / 32, DMODEL / 32), blkT, 0, stream>>>(pw1w, pw1T, DMODEL, 2 * DMODEL);
  wcast_t<<<dim3(DMODEL / 32, DMODEL / 32), blkT, 0, stream>>>(pw2w, pw2T, DMODEL, DMODEL);
  transpose_w<<<62, blk, 0, stream>>>(dww, WTc);

  // ---- FF1 half-step ----
  ln_kernel<true><<<gLN, blk, 0, stream>>>(x, n1g, n1b, Lbf);
  gemm_bf16<1, false, true ><<<gGemmF, blk, 0, stream>>>(Lbf, f1w1T, f1b1, nullptr, 0.f, Hbf, TOK, FDIM, DMODEL);
  gemm_bf16<0, true,  false><<<gGemmD, blk, 0, stream>>>(Hbf, f1w2T, f1b2, x, 0.5f, out, TOK, DMODEL, FDIM);

  // ---- MHSA ----
  ln_kernel<true><<<gLN, blk, 0, stream>>>(out, n2g, n2b, Lbf);
  gemm_bf16<0, false, false><<<gGemmD, blk, 0, stream>>>(Lbf, wqT, bq, nullptr, 0.f, Qf, TOK, DMODEL, DMODEL);
  gemm_bf16<0, false, false><<<gGemmD, blk, 0, stream>>>(Lbf, wkT, bk, nullptr, 0.f, Kf, TOK, DMODEL, DMODEL);
  gemm_bf16<0, false, false><<<gGemmD, blk, 0, stream>>>(Lbf, wvT, bv, nullptr, 0.f, Vf, TOK, DMODEL, DMODEL);
  attn_kernel<<<gAttn, blk, 0, stream>>>(Qf, Kf, Vf, Obf);
  gemm_bf16<0, true,  false><<<gGemmD, blk, 0, stream>>>(Obf, woT, bo, out, 1.0f, out, TOK, DMODEL, DMODEL);

  // ---- conv module ----
  ln_kernel<false><<<gLN, blk, 0, stream>>>(out, n3g, n3b, T1f);
  ln_kernel<true ><<<gLN, blk, 0, stream>>>(T1f, clg, clb, Lbf);
  gemm_bf16<0, false, false><<<gGemm2D, blk, 0, stream>>>(Lbf, pw1T, pw1b, nullptr, 0.f, P1f, TOK, 2 * DMODEL, DMODEL);
  glu_kernel<<<gElem, blk, 0, stream>>>(P1f, Gf);
  dwconv_bn_silu<<<gElem, blk, 0, stream>>>(Gf, WTc, dwb, bng, bnb, bnm, bnv, Cbf);
  gemm_bf16<0, true,  false><<<gGemmD, blk, 0, stream>>>(Cbf, pw2T, pw2b, out, 1.0f, out, TOK, DMODEL, DMODEL);

  // ---- FF2 half-step ----
  ln_kernel<true><<<gLN, blk, 0, stream>>>(out, n4g, n4b, Lbf);
  gemm_bf16<1, false, true ><<<gGemmF, blk, 0, stream>>>(Lbf, f2w1T, f2b1, nullptr, 0.f, Hbf, TOK, FDIM, DMODEL);
  gemm_bf16<0, true,  false><<<gGemmD, blk, 0, stream>>>(Hbf, f2w2T, f2b2, out, 0.5f, out, TOK, DMODEL, FDIM);
}

// Round 3
// 453.204 us; speedup vs baseline: 3.7717x; 1.4546x over previous
//
#include <hip/hip_runtime.h>
#include <math.h>

#define TOK    8192
#define DMODEL 512
#define FDIM   2048
#define NH     8
#define DKH    64
#define SEQ    1024
#define BATCH  8
#define KCONV  31
#define LN_EPS 1e-5f

typedef __attribute__((ext_vector_type(8))) short bf16x8;
typedef __attribute__((ext_vector_type(4))) float f32x4;
typedef unsigned short ushort_t;

__device__ __forceinline__ float sigf(float x) { return 1.0f / (1.0f + expf(-x)); }

__device__ __forceinline__ unsigned short f2bf(float f) {
  unsigned u = __float_as_uint(f);
  u = u + 0x7fffu + ((u >> 16) & 1u);   // RNE
  return (unsigned short)(u >> 16);
}
__device__ __forceinline__ unsigned pk2(float a, float b) {
  return (unsigned)f2bf(a) | ((unsigned)f2bf(b) << 16);
}

// ---------------- weight cast+transpose: [K,N] f32 -> [N,K] bf16 ------------
__global__ __launch_bounds__(256) void wcast_t(const float* __restrict__ w,
                                               ushort_t* __restrict__ wt,
                                               int Kd, int Nd) {
  __shared__ float tile[32][33];
  const int bx = blockIdx.x * 32, by = blockIdx.y * 32;
  const int tx = threadIdx.x, ty = threadIdx.y;  // 32 x 8
#pragma unroll
  for (int i = 0; i < 32; i += 8)
    tile[ty + i][tx] = w[(size_t)(by + ty + i) * Nd + bx + tx];
  __syncthreads();
#pragma unroll
  for (int i = 0; i < 32; i += 8)
    wt[(size_t)(bx + ty + i) * Kd + by + tx] = f2bf(tile[tx][ty + i]);
}

// ---------------- LayerNorm: one wave per 512-wide row ----------------------
template <bool OBF>
__global__ __launch_bounds__(256) void ln_kernel(const float* __restrict__ in,
                                                 const float* __restrict__ g,
                                                 const float* __restrict__ b,
                                                 void* __restrict__ outp) {
  const int wave = threadIdx.x >> 6, lane = threadIdx.x & 63;
  const size_t row = (size_t)blockIdx.x * 4 + wave;
  const float* p = in + row * DMODEL + lane * 8;
  const float4 v0 = *(const float4*)p;
  const float4 v1 = *(const float4*)(p + 4);
  float s  = v0.x + v0.y + v0.z + v0.w + v1.x + v1.y + v1.z + v1.w;
  float ss = v0.x*v0.x + v0.y*v0.y + v0.z*v0.z + v0.w*v0.w
           + v1.x*v1.x + v1.y*v1.y + v1.z*v1.z + v1.w*v1.w;
#pragma unroll
  for (int m = 1; m < 64; m <<= 1) { s += __shfl_xor(s, m); ss += __shfl_xor(ss, m); }
  const float mean = s * (1.0f / DMODEL);
  const float var  = ss * (1.0f / DMODEL) - mean * mean;
  const float rstd = rsqrtf(var + LN_EPS);
  const float4 g0 = *(const float4*)(g + lane * 8);
  const float4 g1 = *(const float4*)(g + lane * 8 + 4);
  const float4 bb0 = *(const float4*)(b + lane * 8);
  const float4 bb1 = *(const float4*)(b + lane * 8 + 4);
  float o[8];
  o[0] = (v0.x - mean) * rstd * g0.x + bb0.x;
  o[1] = (v0.y - mean) * rstd * g0.y + bb0.y;
  o[2] = (v0.z - mean) * rstd * g0.z + bb0.z;
  o[3] = (v0.w - mean) * rstd * g0.w + bb0.w;
  o[4] = (v1.x - mean) * rstd * g1.x + bb1.x;
  o[5] = (v1.y - mean) * rstd * g1.y + bb1.y;
  o[6] = (v1.z - mean) * rstd * g1.z + bb1.z;
  o[7] = (v1.w - mean) * rstd * g1.w + bb1.w;
  if (OBF) {
    uint4 pkv;
    pkv.x = pk2(o[0], o[1]); pkv.y = pk2(o[2], o[3]);
    pkv.z = pk2(o[4], o[5]); pkv.w = pk2(o[6], o[7]);
    *(uint4*)((ushort_t*)outp + row * DMODEL + lane * 8) = pkv;
  } else {
    float4 a, c;
    a.x = o[0]; a.y = o[1]; a.z = o[2]; a.w = o[3];
    c.x = o[4]; c.y = o[5]; c.z = o[6]; c.w = o[7];
    float* q = (float*)outp + row * DMODEL + lane * 8;
    *(float4*)q = a;
    *(float4*)(q + 4) = c;
  }
}

// ---------------- bf16 MFMA GEMM (m97 structure) ----------------------------
template <int ACT, bool RES, bool OBF>
__global__ __launch_bounds__(256) void gemm_bf16(const ushort_t* __restrict__ A,
                                                 const ushort_t* __restrict__ Bt,
                                                 const float* __restrict__ bias,
                                                 const float* __restrict__ Rp,
                                                 float alpha,
                                                 void* __restrict__ Cout,
                                                 int M, int N, int K) {
  __shared__ ushort_t Al[128 * 64];
  __shared__ ushort_t Bl[128 * 64];
  const int t = threadIdx.x;
  const int lane = t & 63;
  const int wid = t >> 6;
  const int wr = wid >> 1, wc = wid & 1;
  const int m0 = blockIdx.y * 128, n0 = blockIdx.x * 128;

  f32x4 acc[4][4];
#pragma unroll
  for (int m = 0; m < 4; ++m)
#pragma unroll
    for (int n = 0; n < 4; ++n) acc[m][n] = (f32x4){0.f, 0.f, 0.f, 0.f};

  const int srow = t >> 3;
  const int scol = (t & 7) * 8;
  const ushort_t* Ag = A + (size_t)(m0 + srow) * K + scol;
  const ushort_t* Bg = Bt + (size_t)(n0 + srow) * K + scol;

  for (int k0 = 0; k0 < K; k0 += 64) {
    __syncthreads();
#pragma unroll
    for (int i = 0; i < 4; ++i) {
      __builtin_amdgcn_global_load_lds(
          (const __attribute__((address_space(1))) unsigned*)(Ag + (size_t)i * 32 * K + k0),
          (__attribute__((address_space(3))) unsigned*)(Al + ((size_t)i * 256 + t) * 8),
          16, 0, 0);
    }
#pragma unroll
    for (int i = 0; i < 4; ++i) {
      __builtin_amdgcn_global_load_lds(
          (const __attribute__((address_space(1))) unsigned*)(Bg + (size_t)i * 32 * K + k0),
          (__attribute__((address_space(3))) unsigned*)(Bl + ((size_t)i * 256 + t) * 8),
          16, 0, 0);
    }
    __syncthreads();

#pragma unroll
    for (int ks = 0; ks < 2; ++ks) {
      const int kk = ks * 32 + (lane >> 4) * 8;
      bf16x8 af[4], bfv[4];
#pragma unroll
      for (int m = 0; m < 4; ++m)
        af[m] = *(const bf16x8*)(Al + (wr * 64 + m * 16 + (lane & 15)) * 64 + kk);
#pragma unroll
      for (int n = 0; n < 4; ++n)
        bfv[n] = *(const bf16x8*)(Bl + (wc * 64 + n * 16 + (lane & 15)) * 64 + kk);
#pragma unroll
      for (int m = 0; m < 4; ++m)
#pragma unroll
        for (int n = 0; n < 4; ++n)
          acc[m][n] = __builtin_amdgcn_mfma_f32_16x16x32_bf16(af[m], bfv[n], acc[m][n], 0, 0, 0);
    }
  }

#pragma unroll
  for (int m = 0; m < 4; ++m) {
    const int row_b = m0 + wr * 64 + m * 16 + (lane >> 4) * 4;
#pragma unroll
    for (int n = 0; n < 4; ++n) {
      const int col = n0 + wc * 64 + n * 16 + (lane & 15);
      const float bv = bias[col];
#pragma unroll
      for (int j = 0; j < 4; ++j) {
        float v = acc[m][n][j] + bv;
        if (ACT == 1) v = fmaxf(v, 0.f);
        const size_t idx = (size_t)(row_b + j) * N + col;
        if (RES) v = Rp[idx] + alpha * v;
        if (OBF) ((ushort_t*)Cout)[idx] = f2bf(v);
        else     ((float*)Cout)[idx] = v;
      }
    }
  }
}

// ---------------- V transpose per head: [b][s][h][d] -> [b][h][d][s] --------
__global__ __launch_bounds__(256) void vtrans(const ushort_t* __restrict__ V,
                                              ushort_t* __restrict__ Vt) {
  __shared__ ushort_t tl[64][72];
  const int st = blockIdx.x;        // s-tile (16)
  const int bh = blockIdx.y;        // b*8+h (64)
  const int b = bh >> 3, h = bh & 7;
  const int t = threadIdx.x;
#pragma unroll
  for (int i = 0; i < 2; ++i) {
    const int chunk = i * 256 + t;
    const int sr = chunk >> 3, c8 = (chunk & 7) * 8;
    *(uint4*)&tl[sr][c8] =
        *(const uint4*)(V + ((size_t)(b * SEQ + st * 64 + sr) * DMODEL) + h * DKH + c8);
  }
  __syncthreads();
#pragma unroll
  for (int i = 0; i < 2; ++i) {
    const int chunk = i * 256 + t;
    const int dr = chunk >> 3, c8 = (chunk & 7) * 8;
    ushort_t tmp[8];
#pragma unroll
    for (int e = 0; e < 8; ++e) tmp[e] = tl[c8 + e][dr];
    *(uint4*)(Vt + ((size_t)(bh * DKH + dr) * SEQ) + st * 64 + c8) = *(uint4*)tmp;
  }
}

// ---------------- MFMA flash attention, bf16 in/out -------------------------
// grid (S/64, H, B), 256 thr (4 waves x 16 q-rows). K,V^T staged in swizzled
// LDS; P transposed through swizzled LDS (wave-local). S kept in f32.
__global__ __launch_bounds__(256) void attn_mfma(const ushort_t* __restrict__ Qm,
                                                 const ushort_t* __restrict__ Km,
                                                 const ushort_t* __restrict__ Vt,
                                                 ushort_t* __restrict__ Om) {
  __shared__ ushort_t Ks[64 * 64];
  __shared__ ushort_t Vs[64 * 64];
  __shared__ ushort_t Ps[64 * 64];
  const int t = threadIdx.x;
  const int l = t & 63;
  const int w = t >> 6;
  const int qb = blockIdx.x, h = blockIdx.y, b = blockIdx.z;
  const size_t baseQ = ((size_t)b * SEQ) * DMODEL + (size_t)h * DKH;
  const size_t baseV = (size_t)(b * NH + h) * DKH * SEQ;

  // Q fragments (A-operand): row = lane&15, k = (lane>>4)*8 + i
  bf16x8 qf[2];
  {
    const int qrow = qb * 64 + w * 16 + (l & 15);
    const ushort_t* qp = Qm + baseQ + (size_t)qrow * DMODEL + ((l >> 4) * 8);
    qf[0] = *(const bf16x8*)(qp);
    qf[1] = *(const bf16x8*)(qp + 32);
  }

  float mrun[4], lrun[4];
  f32x4 o[4];
#pragma unroll
  for (int j = 0; j < 4; ++j) { mrun[j] = -1e30f; lrun[j] = 0.f; }
#pragma unroll
  for (int n = 0; n < 4; ++n) o[n] = (f32x4){0.f, 0.f, 0.f, 0.f};

  for (int kt = 0; kt < SEQ / 64; ++kt) {
    __syncthreads();
    // stage K tile and V^T tile, swizzled (byte ^= (row&7)<<4)
#pragma unroll
    for (int i = 0; i < 2; ++i) {
      const int chunk = i * 256 + t;
      const int r = chunk >> 3, c8 = (chunk & 7) * 8;
      const int sw = r * 128 + ((c8 * 2) ^ ((r & 7) << 4));
      const uint4 kv = *(const uint4*)(Km + baseQ + (size_t)(kt * 64 + r) * DMODEL + c8);
      *(uint4*)((char*)Ks + sw) = kv;
      const uint4 vv = *(const uint4*)(Vt + baseV + (size_t)r * SEQ + kt * 64 + c8);
      *(uint4*)((char*)Vs + sw) = vv;
    }
    __syncthreads();

    // S = Q K^T  (per wave: 16 q-rows x 64 keys)
    f32x4 s[4];
#pragma unroll
    for (int n = 0; n < 4; ++n) s[n] = (f32x4){0.f, 0.f, 0.f, 0.f};
#pragma unroll
    for (int ks = 0; ks < 2; ++ks) {
      const int kk = ks * 64 + (l >> 4) * 16;  // byte offset of k-elems
#pragma unroll
      for (int n = 0; n < 4; ++n) {
        const int krow = n * 16 + (l & 15);
        const bf16x8 kf = *(const bf16x8*)((char*)Ks + krow * 128 + (kk ^ ((krow & 7) << 4)));
        s[n] = __builtin_amdgcn_mfma_f32_16x16x32_bf16(qf[ks], kf, s[n], 0, 0, 0);
      }
    }
#pragma unroll
    for (int n = 0; n < 4; ++n) s[n] = s[n] * 0.125f;  // 1/sqrt(64)

    // online softmax; P -> bf16 via swizzled LDS (wave-local rows)
#pragma unroll
    for (int j = 0; j < 4; ++j) {
      float r0 = fmaxf(fmaxf(s[0][j], s[1][j]), fmaxf(s[2][j], s[3][j]));
      r0 = fmaxf(r0, __shfl_xor(r0, 1));
      r0 = fmaxf(r0, __shfl_xor(r0, 2));
      r0 = fmaxf(r0, __shfl_xor(r0, 4));
      r0 = fmaxf(r0, __shfl_xor(r0, 8));
      const float mn = fmaxf(mrun[j], r0);
      const float cs = expf(mrun[j] - mn);
      const int prow = w * 16 + (l >> 4) * 4 + j;
      const int pswz = (prow & 7) << 4;
      float psum = 0.f;
#pragma unroll
      for (int n = 0; n < 4; ++n) {
        const float p = expf(s[n][j] - mn);
        psum += p;
        const int col2 = (n * 16 + (l & 15)) * 2;
        *(ushort_t*)((char*)Ps + prow * 128 + (col2 ^ pswz)) = f2bf(p);
      }
      psum += __shfl_xor(psum, 1);
      psum += __shfl_xor(psum, 2);
      psum += __shfl_xor(psum, 4);
      psum += __shfl_xor(psum, 8);
      lrun[j] = lrun[j] * cs + psum;
      mrun[j] = mn;
      o[0][j] *= cs; o[1][j] *= cs; o[2][j] *= cs; o[3][j] *= cs;
    }

    // O += P V  (A = P from LDS, B = V^T from LDS)
#pragma unroll
    for (int ks = 0; ks < 2; ++ks) {
      const int kk = ks * 64 + (l >> 4) * 16;
      const int arow = w * 16 + (l & 15);
      const bf16x8 pf = *(const bf16x8*)((char*)Ps + arow * 128 + (kk ^ ((arow & 7) << 4)));
#pragma unroll
      for (int n = 0; n < 4; ++n) {
        const int vrow = n * 16 + (l & 15);
        const bf16x8 vf = *(const bf16x8*)((char*)Vs + vrow * 128 + (kk ^ ((vrow & 7) << 4)));
        o[n] = __builtin_amdgcn_mfma_f32_16x16x32_bf16(pf, vf, o[n], 0, 0, 0);
      }
    }
  }

  // normalize, pack through LDS, coalesced bf16 store
  float inv[4];
#pragma unroll
  for (int j = 0; j < 4; ++j) inv[j] = 1.0f / lrun[j];
#pragma unroll
  for (int j = 0; j < 4; ++j) {
    const int prow = w * 16 + (l >> 4) * 4 + j;
    const int pswz = (prow & 7) << 4;
#pragma unroll
    for (int n = 0; n < 4; ++n) {
      const int col2 = (n * 16 + (l & 15)) * 2;
      *(ushort_t*)((char*)Ps + prow * 128 + (col2 ^ pswz)) = f2bf(o[n][j] * inv[j]);
    }
  }
  __syncthreads();
#pragma unroll
  for (int i = 0; i < 2; ++i) {
    const int chunk = i * 256 + t;
    const int qr = chunk >> 3, c8 = (chunk & 7) * 8;
    const uint4 ov = *(const uint4*)((char*)Ps + qr * 128 + ((c8 * 2) ^ ((qr & 7) << 4)));
    *(uint4*)(Om + baseQ + (size_t)(qb * 64 + qr) * DMODEL + c8) = ov;
  }
}

// ---------------- GLU over channels -----------------------------------------
__global__ __launch_bounds__(256) void glu_kernel(const float* __restrict__ in,
                                                  float* __restrict__ out) {
  const size_t gid = (size_t)blockIdx.x * 256 + threadIdx.x;
  const size_t row = gid >> 7;
  const int c = (int)(gid & 127) * 4;
  const float* p = in + row * (2 * DMODEL);
  const float4 a = *(const float4*)(p + c);
  const float4 g = *(const float4*)(p + DMODEL + c);
  float4 o;
  o.x = a.x * sigf(g.x); o.y = a.y * sigf(g.y);
  o.z = a.z * sigf(g.z); o.w = a.w * sigf(g.w);
  *(float4*)&out[row * DMODEL + c] = o;
}

// ---------------- transpose dw conv weight (D,1,K) -> (K,D) -----------------
__global__ void transpose_w(const float* __restrict__ w, float* __restrict__ wT) {
  const int idx = blockIdx.x * 256 + threadIdx.x;
  if (idx < DMODEL * KCONV) {
    const int d = idx / KCONV, k = idx % KCONV;
    wT[k * DMODEL + d] = w[idx];
  }
}

// ---------------- depthwise conv + bias + BN + SiLU, bf16 out ---------------
__global__ __launch_bounds__(256) void dwconv_bn_silu(const float* __restrict__ in,
                                                      const float* __restrict__ wT,
                                                      const float* __restrict__ dwb,
                                                      const float* __restrict__ bng,
                                                      const float* __restrict__ bnb,
                                                      const float* __restrict__ bnm,
                                                      const float* __restrict__ bnv,
                                                      ushort_t* __restrict__ out) {
  const size_t gid = (size_t)blockIdx.x * 256 + threadIdx.x;
  const int dc = (int)(gid & 127) * 4;
  const int s = (int)((gid >> 7) & (SEQ - 1));
  const int b = (int)(gid >> 17);
  const float* bp = in + (size_t)b * SEQ * DMODEL;
  float ax = 0.f, ay = 0.f, az = 0.f, aw = 0.f;
#pragma unroll
  for (int k = 0; k < KCONV; ++k) {
    const int ssi = s + k - (KCONV / 2);
    if (ssi < 0 || ssi >= SEQ) continue;
    const float4 x = *(const float4*)(bp + (size_t)ssi * DMODEL + dc);
    const float4 w = *(const float4*)(wT + k * DMODEL + dc);
    ax = fmaf(x.x, w.x, ax); ay = fmaf(x.y, w.y, ay);
    az = fmaf(x.z, w.z, az); aw = fmaf(x.w, w.w, aw);
  }
  const float4 bi = *(const float4*)(dwb + dc);
  const float4 mm = *(const float4*)(bnm + dc);
  const float4 vv = *(const float4*)(bnv + dc);
  const float4 gg = *(const float4*)(bng + dc);
  const float4 b2 = *(const float4*)(bnb + dc);
  float v0 = ax + bi.x, v1 = ay + bi.y, v2 = az + bi.z, v3 = aw + bi.w;
  v0 = (v0 - mm.x) * rsqrtf(vv.x + LN_EPS) * gg.x + b2.x;
  v1 = (v1 - mm.y) * rsqrtf(vv.y + LN_EPS) * gg.y + b2.y;
  v2 = (v2 - mm.z) * rsqrtf(vv.z + LN_EPS) * gg.z + b2.z;
  v3 = (v3 - mm.w) * rsqrtf(vv.w + LN_EPS) * gg.w + b2.w;
  v0 = v0 * sigf(v0); v1 = v1 * sigf(v1); v2 = v2 * sigf(v2); v3 = v3 * sigf(v3);
  uint2 o;
  o.x = pk2(v0, v1); o.y = pk2(v2, v3);
  *(uint2*)&out[(((size_t)b * SEQ + s) * DMODEL) + dc] = o;
}

extern "C" void kernel_launch(void* const* d_in, const int* in_sizes, int n_in,
                              void* d_out, int out_size, void* d_ws, size_t ws_size,
                              hipStream_t stream) {
  const float* x    = (const float*)d_in[0];
  const float* n1g  = (const float*)d_in[1];
  const float* n1b  = (const float*)d_in[2];
  const float* n2g  = (const float*)d_in[3];
  const float* n2b  = (const float*)d_in[4];
  const float* n3g  = (const float*)d_in[5];
  const float* n3b  = (const float*)d_in[6];
  const float* n4g  = (const float*)d_in[7];
  const float* n4b  = (const float*)d_in[8];
  const float* clg  = (const float*)d_in[9];
  const float* clb  = (const float*)d_in[10];
  const float* f1w1 = (const float*)d_in[11];
  const float* f1b1 = (const float*)d_in[12];
  const float* f1w2 = (const float*)d_in[13];
  const float* f1b2 = (const float*)d_in[14];
  const float* f2w1 = (const float*)d_in[15];
  const float* f2b1 = (const float*)d_in[16];
  const float* f2w2 = (const float*)d_in[17];
  const float* f2b2 = (const float*)d_in[18];
  const float* wq   = (const float*)d_in[19];
  const float* bq   = (const float*)d_in[20];
  const float* wk   = (const float*)d_in[21];
  const float* bk   = (const float*)d_in[22];
  const float* wv   = (const float*)d_in[23];
  const float* bv   = (const float*)d_in[24];
  const float* wo   = (const float*)d_in[25];
  const float* bo   = (const float*)d_in[26];
  const float* pw1w = (const float*)d_in[27];
  const float* pw1b = (const float*)d_in[28];
  const float* dww  = (const float*)d_in[29];
  const float* dwb  = (const float*)d_in[30];
  const float* bng  = (const float*)d_in[31];
  const float* bnb  = (const float*)d_in[32];
  const float* bnm  = (const float*)d_in[33];
  const float* bnv  = (const float*)d_in[34];
  const float* pw2w = (const float*)d_in[35];
  const float* pw2b = (const float*)d_in[36];

  char* wsb = (char*)d_ws;
  const size_t MB = 1ull << 20;
  ushort_t* Wbf    = (ushort_t*)(wsb + 0);
  ushort_t* f1w1T  = Wbf + 0;
  ushort_t* f1w2T  = Wbf + (1ull << 20);
  ushort_t* f2w1T  = Wbf + (2ull << 20);
  ushort_t* f2w2T  = Wbf + (3ull << 20);
  ushort_t* wqT    = Wbf + (4ull << 20);
  ushort_t* wkT    = Wbf + (4ull << 20) + (256ull << 10);
  ushort_t* wvT    = Wbf + (4ull << 20) + (512ull << 10);
  ushort_t* woT    = Wbf + (4ull << 20) + (768ull << 10);
  ushort_t* pw1T   = Wbf + (5ull << 20);
  ushort_t* pw2T   = Wbf + (5ull << 20) + (512ull << 10);
  float*    WTc    = (float*)(wsb + 12 * MB);
  ushort_t* Lbf    = (ushort_t*)(wsb + 13 * MB);      // 8 MB
  ushort_t* Hbf    = (ushort_t*)(wsb + 21 * MB);      // 32 MB region
  float*    P1f    = (float*)(wsb + 21 * MB);
  // attention bf16 buffers (8 MB each)
  ushort_t* Qbf    = (ushort_t*)(wsb + 53 * MB);
  ushort_t* Kbf    = (ushort_t*)(wsb + 61 * MB);
  ushort_t* Vbf    = (ushort_t*)(wsb + 69 * MB);
  ushort_t* Vtb    = (ushort_t*)(wsb + 77 * MB);
  // conv-module f32 temps (reuse attn region; attn is finished by then)
  float*    T1f    = (float*)(wsb + 53 * MB);
  float*    Gf     = (float*)(wsb + 69 * MB);
  ushort_t* Obf    = (ushort_t*)(wsb + 101 * MB);
  ushort_t* Cbf    = Obf;
  float* out = (float*)d_out;

  const dim3 blk(256);
  const dim3 blkT(32, 8);
  const dim3 gLN(TOK / 4);
  const dim3 gGemmF(FDIM / 128, TOK / 128);
  const dim3 gGemmD(DMODEL / 128, TOK / 128);
  const dim3 gGemm2D(2 * DMODEL / 128, TOK / 128);
  const dim3 gAttn(SEQ / 64, NH, BATCH);
  const dim3 gVt(SEQ / 64, BATCH * NH);
  const dim3 gElem(TOK * 128 / 256);

  // ---- weight preprocessing ----
  wcast_t<<<dim3(FDIM / 32, DMODEL / 32), blkT, 0, stream>>>(f1w1, f1w1T, DMODEL, FDIM);
  wcast_t<<<dim3(DMODEL / 32, FDIM / 32), blkT, 0, stream>>>(f1w2, f1w2T, FDIM, DMODEL);
  wcast_t<<<dim3(FDIM / 32, DMODEL / 32), blkT, 0, stream>>>(f2w1, f2w1T, DMODEL, FDIM);
  wcast_t<<<dim3(DMODEL / 32, FDIM / 32), blkT, 0, stream>>>(f2w2, f2w2T, FDIM, DMODEL);
  wcast_t<<<dim3(DMODEL / 32, DMODEL / 32), blkT, 0, stream>>>(wq, wqT, DMODEL, DMODEL);
  wcast_t<<<dim3(DMODEL / 32, DMODEL / 32), blkT, 0, stream>>>(wk, wkT, DMODEL, DMODEL);
  wcast_t<<<dim3(DMODEL / 32, DMODEL / 32), blkT, 0, stream>>>(wv, wvT, DMODEL, DMODEL);
  wcast_t<<<dim3(DMODEL / 32, DMODEL / 32), blkT, 0, stream>>>(wo, woT, DMODEL, DMODEL);
  wcast_t<<<dim3(2 * DMODEL / 32, DMODEL / 32), blkT, 0, stream>>>(pw1w, pw1T, DMODEL, 2 * DMODEL);
  wcast_t<<<dim3(DMODEL / 32, DMODEL / 32), blkT, 0, stream>>>(pw2w, pw2T, DMODEL, DMODEL);
  transpose_w<<<62, blk, 0, stream>>>(dww, WTc);

  // ---- FF1 half-step ----
  ln_kernel<true><<<gLN, blk, 0, stream>>>(x, n1g, n1b, Lbf);
  gemm_bf16<1, false, true ><<<gGemmF, blk, 0, stream>>>(Lbf, f1w1T, f1b1, nullptr, 0.f, Hbf, TOK, FDIM, DMODEL);
  gemm_bf16<0, true,  false><<<gGemmD, blk, 0, stream>>>(Hbf, f1w2T, f1b2, x, 0.5f, out, TOK, DMODEL, FDIM);

  // ---- MHSA ----
  ln_kernel<true><<<gLN, blk, 0, stream>>>(out, n2g, n2b, Lbf);
  gemm_bf16<0, false, true><<<gGemmD, blk, 0, stream>>>(Lbf, wqT, bq, nullptr, 0.f, Qbf, TOK, DMODEL, DMODEL);
  gemm_bf16<0, false, true><<<gGemmD, blk, 0, stream>>>(Lbf, wkT, bk, nullptr, 0.f, Kbf, TOK, DMODEL, DMODEL);
  gemm_bf16<0, false, true><<<gGemmD, blk, 0, stream>>>(Lbf, wvT, bv, nullptr, 0.f, Vbf, TOK, DMODEL, DMODEL);
  vtrans<<<gVt, blk, 0, stream>>>(Vbf, Vtb);
  attn_mfma<<<gAttn, blk, 0, stream>>>(Qbf, Kbf, Vtb, Obf);
  gemm_bf16<0, true,  false><<<gGemmD, blk, 0, stream>>>(Obf, woT, bo, out, 1.0f, out, TOK, DMODEL, DMODEL);

  // ---- conv module ----
  ln_kernel<false><<<gLN, blk, 0, stream>>>(out, n3g, n3b, T1f);
  ln_kernel<true ><<<gLN, blk, 0, stream>>>(T1f, clg, clb, Lbf);
  gemm_bf16<0, false, false><<<gGemm2D, blk, 0, stream>>>(Lbf, pw1T, pw1b, nullptr, 0.f, P1f, TOK, 2 * DMODEL, DMODEL);
  glu_kernel<<<gElem, blk, 0, stream>>>(P1f, Gf);
  dwconv_bn_silu<<<gElem, blk, 0, stream>>>(Gf, WTc, dwb, bng, bnb, bnm, bnv, Cbf);
  gemm_bf16<0, true,  false><<<gGemmD, blk, 0, stream>>>(Cbf, pw2T, pw2b, out, 1.0f, out, TOK, DMODEL, DMODEL);

  // ---- FF2 half-step ----
  ln_kernel<true><<<gLN, blk, 0, stream>>>(out, n4g, n4b, Lbf);
  gemm_bf16<1, false, true ><<<gGemmF, blk, 0, stream>>>(Lbf, f2w1T, f2b1, nullptr, 0.f, Hbf, TOK, FDIM, DMODEL);
  gemm_bf16<0, true,  false><<<gGemmD, blk, 0, stream>>>(Hbf, f2w2T, f2b2, out, 0.5f, out, TOK, DMODEL, FDIM);
}

// Round 4
// 362.020 us; speedup vs baseline: 4.7217x; 1.2519x over previous
//
#include <hip/hip_runtime.h>
#include <math.h>

#define TOK    8192
#define DMODEL 512
#define FDIM   2048
#define NH     8
#define DKH    64
#define SEQ    1024
#define BATCH  8
#define KCONV  31
#define LN_EPS 1e-5f

typedef __attribute__((ext_vector_type(8))) short bf16x8;
typedef __attribute__((ext_vector_type(4))) float f32x4;
typedef unsigned short ushort_t;

__device__ __forceinline__ float sigf(float x) { return 1.0f / (1.0f + __expf(-x)); }

__device__ __forceinline__ unsigned short f2bf(float f) {
  unsigned u = __float_as_uint(f);
  u = u + 0x7fffu + ((u >> 16) & 1u);   // RNE
  return (unsigned short)(u >> 16);
}
__device__ __forceinline__ unsigned pk2(float a, float b) {
  return (unsigned)f2bf(a) | ((unsigned)f2bf(b) << 16);
}
__device__ __forceinline__ float bf2f(ushort_t u) {
  return __uint_as_float((unsigned)u << 16);
}

// ---------------- all-weights cast+transpose in ONE dispatch ----------------
struct WJob { const float* src; ushort_t* dst; int K, N, t0; };
struct WJobs { WJob j[10]; };

__global__ __launch_bounds__(256) void wcast_all(WJobs jobs) {
  __shared__ float tile[32][33];
  const int t = blockIdx.x;
  int i = 0;
#pragma unroll
  for (int k = 1; k < 10; ++k) if (t >= jobs.j[k].t0) i = k;
  const WJob jb = jobs.j[i];
  const int local = t - jb.t0;
  const int ntx = jb.N >> 5;
  const int bx = (local % ntx) * 32, by = (local / ntx) * 32;
  const int tx = threadIdx.x, ty = threadIdx.y;  // 32 x 8
#pragma unroll
  for (int r = 0; r < 32; r += 8)
    tile[ty + r][tx] = jb.src[(size_t)(by + ty + r) * jb.N + bx + tx];
  __syncthreads();
#pragma unroll
  for (int r = 0; r < 32; r += 8)
    jb.dst[(size_t)(bx + ty + r) * jb.K + by + tx] = f2bf(tile[tx][ty + r]);
}

// ---------------- misc prep: dw-weight transpose + qkv bias concat ----------
__global__ void misc_prep(const float* __restrict__ w, float* __restrict__ wT,
                          const float* __restrict__ bq, const float* __restrict__ bk,
                          const float* __restrict__ bv, float* __restrict__ bcat) {
  const int idx = blockIdx.x * 256 + threadIdx.x;
  if (idx < DMODEL * KCONV) {
    const int d = idx / KCONV, k = idx % KCONV;
    wT[k * DMODEL + d] = w[idx];
  } else if (idx < DMODEL * KCONV + 3 * DMODEL) {
    const int c = idx - DMODEL * KCONV;
    bcat[c] = (c < DMODEL) ? bq[c] : (c < 2 * DMODEL ? bk[c - DMODEL] : bv[c - 2 * DMODEL]);
  }
}

// ---------------- LayerNorm: one wave per 512-wide row ----------------------
template <bool OBF>
__global__ __launch_bounds__(256) void ln_kernel(const float* __restrict__ in,
                                                 const float* __restrict__ g,
                                                 const float* __restrict__ b,
                                                 void* __restrict__ outp) {
  const int wave = threadIdx.x >> 6, lane = threadIdx.x & 63;
  const size_t row = (size_t)blockIdx.x * 4 + wave;
  const float* p = in + row * DMODEL + lane * 8;
  const float4 v0 = *(const float4*)p;
  const float4 v1 = *(const float4*)(p + 4);
  float s  = v0.x + v0.y + v0.z + v0.w + v1.x + v1.y + v1.z + v1.w;
  float ss = v0.x*v0.x + v0.y*v0.y + v0.z*v0.z + v0.w*v0.w
           + v1.x*v1.x + v1.y*v1.y + v1.z*v1.z + v1.w*v1.w;
#pragma unroll
  for (int m = 1; m < 64; m <<= 1) { s += __shfl_xor(s, m); ss += __shfl_xor(ss, m); }
  const float mean = s * (1.0f / DMODEL);
  const float var  = ss * (1.0f / DMODEL) - mean * mean;
  const float rstd = rsqrtf(var + LN_EPS);
  const float4 g0 = *(const float4*)(g + lane * 8);
  const float4 g1 = *(const float4*)(g + lane * 8 + 4);
  const float4 bb0 = *(const float4*)(b + lane * 8);
  const float4 bb1 = *(const float4*)(b + lane * 8 + 4);
  float o[8];
  o[0] = (v0.x - mean) * rstd * g0.x + bb0.x;
  o[1] = (v0.y - mean) * rstd * g0.y + bb0.y;
  o[2] = (v0.z - mean) * rstd * g0.z + bb0.z;
  o[3] = (v0.w - mean) * rstd * g0.w + bb0.w;
  o[4] = (v1.x - mean) * rstd * g1.x + bb1.x;
  o[5] = (v1.y - mean) * rstd * g1.y + bb1.y;
  o[6] = (v1.z - mean) * rstd * g1.z + bb1.z;
  o[7] = (v1.w - mean) * rstd * g1.w + bb1.w;
  if (OBF) {
    uint4 pkv;
    pkv.x = pk2(o[0], o[1]); pkv.y = pk2(o[2], o[3]);
    pkv.z = pk2(o[4], o[5]); pkv.w = pk2(o[6], o[7]);
    *(uint4*)((ushort_t*)outp + row * DMODEL + lane * 8) = pkv;
  } else {
    float4 a, c;
    a.x = o[0]; a.y = o[1]; a.z = o[2]; a.w = o[3];
    c.x = o[4]; c.y = o[5]; c.z = o[6]; c.w = o[7];
    float* q = (float*)outp + row * DMODEL + lane * 8;
    *(float4*)q = a;
    *(float4*)(q + 4) = c;
  }
}

// ---------------- fused double LayerNorm (norm3 then conv_ln), bf16 out -----
__global__ __launch_bounds__(256) void ln2_kernel(const float* __restrict__ in,
                                                  const float* __restrict__ g1,
                                                  const float* __restrict__ b1,
                                                  const float* __restrict__ g2,
                                                  const float* __restrict__ b2,
                                                  ushort_t* __restrict__ outp) {
  const int wave = threadIdx.x >> 6, lane = threadIdx.x & 63;
  const size_t row = (size_t)blockIdx.x * 4 + wave;
  const float* p = in + row * DMODEL + lane * 8;
  float v[8];
  {
    const float4 v0 = *(const float4*)p;
    const float4 v1 = *(const float4*)(p + 4);
    v[0]=v0.x; v[1]=v0.y; v[2]=v0.z; v[3]=v0.w;
    v[4]=v1.x; v[5]=v1.y; v[6]=v1.z; v[7]=v1.w;
  }
  float s = 0.f, ss = 0.f;
#pragma unroll
  for (int e = 0; e < 8; ++e) { s += v[e]; ss += v[e]*v[e]; }
#pragma unroll
  for (int m = 1; m < 64; m <<= 1) { s += __shfl_xor(s, m); ss += __shfl_xor(ss, m); }
  float mean = s * (1.0f / DMODEL);
  float rstd = rsqrtf(ss * (1.0f / DMODEL) - mean * mean + LN_EPS);
  const float4 ga = *(const float4*)(g1 + lane * 8);
  const float4 gb = *(const float4*)(g1 + lane * 8 + 4);
  const float4 ba = *(const float4*)(b1 + lane * 8);
  const float4 bb = *(const float4*)(b1 + lane * 8 + 4);
  const float gg1[8] = {ga.x,ga.y,ga.z,ga.w,gb.x,gb.y,gb.z,gb.w};
  const float bb1[8] = {ba.x,ba.y,ba.z,ba.w,bb.x,bb.y,bb.z,bb.w};
#pragma unroll
  for (int e = 0; e < 8; ++e) v[e] = (v[e] - mean) * rstd * gg1[e] + bb1[e];
  // second LN in-register
  s = 0.f; ss = 0.f;
#pragma unroll
  for (int e = 0; e < 8; ++e) { s += v[e]; ss += v[e]*v[e]; }
#pragma unroll
  for (int m = 1; m < 64; m <<= 1) { s += __shfl_xor(s, m); ss += __shfl_xor(ss, m); }
  mean = s * (1.0f / DMODEL);
  rstd = rsqrtf(ss * (1.0f / DMODEL) - mean * mean + LN_EPS);
  const float4 gc = *(const float4*)(g2 + lane * 8);
  const float4 gd = *(const float4*)(g2 + lane * 8 + 4);
  const float4 bc = *(const float4*)(b2 + lane * 8);
  const float4 bd = *(const float4*)(b2 + lane * 8 + 4);
  const float gg2[8] = {gc.x,gc.y,gc.z,gc.w,gd.x,gd.y,gd.z,gd.w};
  const float bb2[8] = {bc.x,bc.y,bc.z,bc.w,bd.x,bd.y,bd.z,bd.w};
  float o[8];
#pragma unroll
  for (int e = 0; e < 8; ++e) o[e] = (v[e] - mean) * rstd * gg2[e] + bb2[e];
  uint4 pkv;
  pkv.x = pk2(o[0], o[1]); pkv.y = pk2(o[2], o[3]);
  pkv.z = pk2(o[4], o[5]); pkv.w = pk2(o[6], o[7]);
  *(uint4*)(outp + row * DMODEL + lane * 8) = pkv;
}

// ---------------- bf16 MFMA GEMM (m97 structure), TN = 128 or 64 ------------
// A [M,K] bf16; Bt [N,K] bf16. C = act(A@B + bias); QSC: cols<512 scaled 1/8.
// RES: C = Rp + alpha*C. OBF: bf16 out. 128xTN tile, BK=64, 4 waves (2x2).
template <int TN, int ACT, bool RES, bool OBF, bool QSC>
__global__ __launch_bounds__(256) void gemm_bf16(const ushort_t* __restrict__ A,
                                                 const ushort_t* __restrict__ Bt,
                                                 const float* __restrict__ bias,
                                                 const float* __restrict__ Rp,
                                                 float alpha,
                                                 void* __restrict__ Cout,
                                                 int M, int N, int K) {
  constexpr int NF = TN / 32;       // B n-frags per wave (4 or 2)
  constexpr int NB = TN / 32;       // B staging iters (4 or 2)
  __shared__ ushort_t Al[128 * 64];
  __shared__ ushort_t Bl[TN * 64];
  const int t = threadIdx.x;
  const int lane = t & 63;
  const int wid = t >> 6;
  const int wr = wid >> 1, wc = wid & 1;
  const int m0 = blockIdx.y * 128, n0 = blockIdx.x * TN;

  f32x4 acc[4][NF];
#pragma unroll
  for (int m = 0; m < 4; ++m)
#pragma unroll
    for (int n = 0; n < NF; ++n) acc[m][n] = (f32x4){0.f, 0.f, 0.f, 0.f};

  const int srow = t >> 3;
  const int scol = (t & 7) * 8;
  const ushort_t* Ag = A + (size_t)(m0 + srow) * K + scol;
  const ushort_t* Bg = Bt + (size_t)(n0 + srow) * K + scol;

  for (int k0 = 0; k0 < K; k0 += 64) {
    __syncthreads();
#pragma unroll
    for (int i = 0; i < 4; ++i) {
      __builtin_amdgcn_global_load_lds(
          (const __attribute__((address_space(1))) unsigned*)(Ag + (size_t)i * 32 * K + k0),
          (__attribute__((address_space(3))) unsigned*)(Al + ((size_t)i * 256 + t) * 8),
          16, 0, 0);
    }
#pragma unroll
    for (int i = 0; i < NB; ++i) {
      __builtin_amdgcn_global_load_lds(
          (const __attribute__((address_space(1))) unsigned*)(Bg + (size_t)i * 32 * K + k0),
          (__attribute__((address_space(3))) unsigned*)(Bl + ((size_t)i * 256 + t) * 8),
          16, 0, 0);
    }
    __syncthreads();

#pragma unroll
    for (int ks = 0; ks < 2; ++ks) {
      const int kk = ks * 32 + (lane >> 4) * 8;
      bf16x8 af[4], bfv[NF];
#pragma unroll
      for (int m = 0; m < 4; ++m)
        af[m] = *(const bf16x8*)(Al + (wr * 64 + m * 16 + (lane & 15)) * 64 + kk);
#pragma unroll
      for (int n = 0; n < NF; ++n)
        bfv[n] = *(const bf16x8*)(Bl + (wc * (TN / 2) + n * 16 + (lane & 15)) * 64 + kk);
#pragma unroll
      for (int m = 0; m < 4; ++m)
#pragma unroll
        for (int n = 0; n < NF; ++n)
          acc[m][n] = __builtin_amdgcn_mfma_f32_16x16x32_bf16(af[m], bfv[n], acc[m][n], 0, 0, 0);
    }
  }

#pragma unroll
  for (int m = 0; m < 4; ++m) {
    const int row_b = m0 + wr * 64 + m * 16 + (lane >> 4) * 4;
#pragma unroll
    for (int n = 0; n < NF; ++n) {
      const int col = n0 + wc * (TN / 2) + n * 16 + (lane & 15);
      const float bv = bias[col];
#pragma unroll
      for (int j = 0; j < 4; ++j) {
        float v = acc[m][n][j] + bv;
        if (ACT == 1) v = fmaxf(v, 0.f);
        if (QSC) v *= (col < DMODEL ? 0.125f : 1.0f);
        const size_t idx = (size_t)(row_b + j) * N + col;
        if (RES) v = Rp[idx] + alpha * v;
        if (OBF) ((ushort_t*)Cout)[idx] = f2bf(v);
        else     ((float*)Cout)[idx] = v;
      }
    }
  }
}

// ---------------- V transpose per head: QKV[b][s][1024+h*64+d] -> [bh][d][s] -
__global__ __launch_bounds__(256) void vtrans(const ushort_t* __restrict__ QKV,
                                              ushort_t* __restrict__ Vt) {
  __shared__ ushort_t tl[64][72];
  const int st = blockIdx.x;        // s-tile (16)
  const int bh = blockIdx.y;        // b*8+h (64)
  const int b = bh >> 3, h = bh & 7;
  const int t = threadIdx.x;
#pragma unroll
  for (int i = 0; i < 2; ++i) {
    const int chunk = i * 256 + t;
    const int sr = chunk >> 3, c8 = (chunk & 7) * 8;
    *(uint4*)&tl[sr][c8] =
        *(const uint4*)(QKV + ((size_t)(b * SEQ + st * 64 + sr) * (3 * DMODEL)) + 2 * DMODEL + h * DKH + c8);
  }
  __syncthreads();
#pragma unroll
  for (int i = 0; i < 2; ++i) {
    const int chunk = i * 256 + t;
    const int dr = chunk >> 3, c8 = (chunk & 7) * 8;
    ushort_t tmp[8];
#pragma unroll
    for (int e = 0; e < 8; ++e) tmp[e] = tl[c8 + e][dr];
    *(uint4*)(Vt + ((size_t)(bh * DKH + dr) * SEQ) + st * 64 + c8) = *(uint4*)tmp;
  }
}

// ---------------- MFMA flash attention, KVBLK=128 ---------------------------
// grid (S/64, H, B), 256 thr (4 waves x 16 q-rows). Q pre-scaled by 1/8.
__global__ __launch_bounds__(256) void attn_mfma(const ushort_t* __restrict__ QKV,
                                                 const ushort_t* __restrict__ Vt,
                                                 ushort_t* __restrict__ Om) {
  __shared__ ushort_t Ks[128 * 64];   // [key][dk]   row = 128 B, swizzled
  __shared__ ushort_t Vs[64 * 128];   // [dk][key]   row = 256 B, swizzled
  __shared__ ushort_t Ps[64 * 128];   // [q][key]    row = 256 B, swizzled
  const int t = threadIdx.x;
  const int l = t & 63;
  const int w = t >> 6;
  const int qb = blockIdx.x, h = blockIdx.y, b = blockIdx.z;
  const size_t rowstr = 3 * DMODEL;
  const size_t baseQ = ((size_t)b * SEQ) * rowstr + (size_t)h * DKH;
  const size_t baseK = baseQ + DMODEL;
  const size_t baseV = (size_t)(b * NH + h) * DKH * SEQ;
  const size_t baseO = ((size_t)b * SEQ) * DMODEL + (size_t)h * DKH;

  bf16x8 qf[2];
  {
    const int qrow = qb * 64 + w * 16 + (l & 15);
    const ushort_t* qp = QKV + baseQ + (size_t)qrow * rowstr + ((l >> 4) * 8);
    qf[0] = *(const bf16x8*)(qp);
    qf[1] = *(const bf16x8*)(qp + 32);
  }

  float mrun[4], lrun[4];
  f32x4 o[4];
#pragma unroll
  for (int j = 0; j < 4; ++j) { mrun[j] = -1e30f; lrun[j] = 0.f; }
#pragma unroll
  for (int n = 0; n < 4; ++n) o[n] = (f32x4){0.f, 0.f, 0.f, 0.f};

  for (int kt = 0; kt < SEQ / 128; ++kt) {
    __syncthreads();
    // stage K tile [128][64] (rows 128B) and V^T tile [64][128] (rows 256B)
#pragma unroll
    for (int i = 0; i < 4; ++i) {
      const int chunk = i * 256 + t;
      {
        const int r = chunk >> 3, c8 = (chunk & 7) * 8;
        const uint4 kv = *(const uint4*)(QKV + baseK + (size_t)(kt * 128 + r) * rowstr + c8);
        *(uint4*)((char*)Ks + r * 128 + ((c8 * 2) ^ ((r & 7) << 4))) = kv;
      }
      {
        const int r = chunk >> 4, c8 = (chunk & 15) * 8;
        const uint4 vv = *(const uint4*)(Vt + baseV + (size_t)r * SEQ + kt * 128 + c8);
        *(uint4*)((char*)Vs + r * 256 + ((c8 * 2) ^ ((r & 15) << 4))) = vv;
      }
    }
    __syncthreads();

    // S = Q K^T : 16 q-rows x 128 keys per wave
    f32x4 s[8];
#pragma unroll
    for (int n = 0; n < 8; ++n) s[n] = (f32x4){0.f, 0.f, 0.f, 0.f};
#pragma unroll
    for (int ks = 0; ks < 2; ++ks) {
      const int kk = ks * 64 + (l >> 4) * 16;
#pragma unroll
      for (int n = 0; n < 8; ++n) {
        const int krow = n * 16 + (l & 15);
        const bf16x8 kf = *(const bf16x8*)((char*)Ks + krow * 128 + (kk ^ ((krow & 7) << 4)));
        s[n] = __builtin_amdgcn_mfma_f32_16x16x32_bf16(qf[ks], kf, s[n], 0, 0, 0);
      }
    }

    // online softmax; P -> bf16 via swizzled LDS (wave-local rows)
#pragma unroll
    for (int j = 0; j < 4; ++j) {
      float r0 = s[0][j];
#pragma unroll
      for (int n = 1; n < 8; ++n) r0 = fmaxf(r0, s[n][j]);
      r0 = fmaxf(r0, __shfl_xor(r0, 1));
      r0 = fmaxf(r0, __shfl_xor(r0, 2));
      r0 = fmaxf(r0, __shfl_xor(r0, 4));
      r0 = fmaxf(r0, __shfl_xor(r0, 8));
      const float mn = fmaxf(mrun[j], r0);
      const float cs = __expf(mrun[j] - mn);
      const int prow = w * 16 + (l >> 4) * 4 + j;
      const int pswz = (prow & 15) << 4;
      float psum = 0.f;
#pragma unroll
      for (int n = 0; n < 8; ++n) {
        const float p = __expf(s[n][j] - mn);
        psum += p;
        const int col2 = (n * 16 + (l & 15)) * 2;
        *(ushort_t*)((char*)Ps + prow * 256 + (col2 ^ pswz)) = f2bf(p);
      }
      psum += __shfl_xor(psum, 1);
      psum += __shfl_xor(psum, 2);
      psum += __shfl_xor(psum, 4);
      psum += __shfl_xor(psum, 8);
      lrun[j] = lrun[j] * cs + psum;
      mrun[j] = mn;
      o[0][j] *= cs; o[1][j] *= cs; o[2][j] *= cs; o[3][j] *= cs;
    }

    // O += P V  (A = P rows, B = V^T rows)
#pragma unroll
    for (int ks = 0; ks < 4; ++ks) {
      const int kk = ks * 64 + (l >> 4) * 16;
      const int arow = w * 16 + (l & 15);
      const bf16x8 pf = *(const bf16x8*)((char*)Ps + arow * 256 + (kk ^ ((arow & 15) << 4)));
#pragma unroll
      for (int n = 0; n < 4; ++n) {
        const int vrow = n * 16 + (l & 15);
        const bf16x8 vf = *(const bf16x8*)((char*)Vs + vrow * 256 + (kk ^ ((vrow & 15) << 4)));
        o[n] = __builtin_amdgcn_mfma_f32_16x16x32_bf16(pf, vf, o[n], 0, 0, 0);
      }
    }
  }

  // normalize, repack through LDS, coalesced bf16 store
  float inv[4];
#pragma unroll
  for (int j = 0; j < 4; ++j) inv[j] = 1.0f / lrun[j];
#pragma unroll
  for (int j = 0; j < 4; ++j) {
    const int prow = w * 16 + (l >> 4) * 4 + j;
    const int pswz = (prow & 15) << 4;
#pragma unroll
    for (int n = 0; n < 4; ++n) {
      const int col2 = (n * 16 + (l & 15)) * 2;
      *(ushort_t*)((char*)Ps + prow * 256 + (col2 ^ pswz)) = f2bf(o[n][j] * inv[j]);
    }
  }
  __syncthreads();
#pragma unroll
  for (int i = 0; i < 2; ++i) {
    const int chunk = i * 256 + t;
    const int qr = chunk >> 3, c8 = (chunk & 7) * 8;
    const uint4 ov = *(const uint4*)((char*)Ps + qr * 256 + ((c8 * 2) ^ ((qr & 15) << 4)));
    *(uint4*)(Om + baseO + (size_t)(qb * 64 + qr) * DMODEL + c8) = ov;
  }
}

// ---------------- GLU over channels, bf16 in/out ----------------------------
__global__ __launch_bounds__(256) void glu_kernel(const ushort_t* __restrict__ in,
                                                  ushort_t* __restrict__ out) {
  const size_t gid = (size_t)blockIdx.x * 256 + threadIdx.x;
  const size_t row = gid >> 7;
  const int c = (int)(gid & 127) * 4;
  const ushort_t* p = in + row * (2 * DMODEL);
  ushort_t a[4], g[4];
  *(uint2*)a = *(const uint2*)(p + c);
  *(uint2*)g = *(const uint2*)(p + DMODEL + c);
  uint2 o;
  o.x = pk2(bf2f(a[0]) * sigf(bf2f(g[0])), bf2f(a[1]) * sigf(bf2f(g[1])));
  o.y = pk2(bf2f(a[2]) * sigf(bf2f(g[2])), bf2f(a[3]) * sigf(bf2f(g[3])));
  *(uint2*)&out[row * DMODEL + c] = o;
}

// ---------------- depthwise conv + bias + BN + SiLU, bf16 in/out ------------
__global__ __launch_bounds__(256) void dwconv_bn_silu(const ushort_t* __restrict__ in,
                                                      const float* __restrict__ wT,
                                                      const float* __restrict__ dwb,
                                                      const float* __restrict__ bng,
                                                      const float* __restrict__ bnb,
                                                      const float* __restrict__ bnm,
                                                      const float* __restrict__ bnv,
                                                      ushort_t* __restrict__ out) {
  const size_t gid = (size_t)blockIdx.x * 256 + threadIdx.x;
  const int dc = (int)(gid & 127) * 4;
  const int s = (int)((gid >> 7) & (SEQ - 1));
  const int b = (int)(gid >> 17);
  const ushort_t* bp = in + (size_t)b * SEQ * DMODEL;
  float ax = 0.f, ay = 0.f, az = 0.f, aw = 0.f;
#pragma unroll
  for (int k = 0; k < KCONV; ++k) {
    const int ssi = s + k - (KCONV / 2);
    if (ssi < 0 || ssi >= SEQ) continue;
    ushort_t xv[4];
    *(uint2*)xv = *(const uint2*)(bp + (size_t)ssi * DMODEL + dc);
    const float4 w = *(const float4*)(wT + k * DMODEL + dc);
    ax = fmaf(bf2f(xv[0]), w.x, ax); ay = fmaf(bf2f(xv[1]), w.y, ay);
    az = fmaf(bf2f(xv[2]), w.z, az); aw = fmaf(bf2f(xv[3]), w.w, aw);
  }
  const float4 bi = *(const float4*)(dwb + dc);
  const float4 mm = *(const float4*)(bnm + dc);
  const float4 vv = *(const float4*)(bnv + dc);
  const float4 gg = *(const float4*)(bng + dc);
  const float4 b2 = *(const float4*)(bnb + dc);
  float v0 = ax + bi.x, v1 = ay + bi.y, v2 = az + bi.z, v3 = aw + bi.w;
  v0 = (v0 - mm.x) * rsqrtf(vv.x + LN_EPS) * gg.x + b2.x;
  v1 = (v1 - mm.y) * rsqrtf(vv.y + LN_EPS) * gg.y + b2.y;
  v2 = (v2 - mm.z) * rsqrtf(vv.z + LN_EPS) * gg.z + b2.z;
  v3 = (v3 - mm.w) * rsqrtf(vv.w + LN_EPS) * gg.w + b2.w;
  v0 = v0 * sigf(v0); v1 = v1 * sigf(v1); v2 = v2 * sigf(v2); v3 = v3 * sigf(v3);
  uint2 o;
  o.x = pk2(v0, v1); o.y = pk2(v2, v3);
  *(uint2*)&out[(((size_t)b * SEQ + s) * DMODEL) + dc] = o;
}

extern "C" void kernel_launch(void* const* d_in, const int* in_sizes, int n_in,
                              void* d_out, int out_size, void* d_ws, size_t ws_size,
                              hipStream_t stream) {
  const float* x    = (const float*)d_in[0];
  const float* n1g  = (const float*)d_in[1];
  const float* n1b  = (const float*)d_in[2];
  const float* n2g  = (const float*)d_in[3];
  const float* n2b  = (const float*)d_in[4];
  const float* n3g  = (const float*)d_in[5];
  const float* n3b  = (const float*)d_in[6];
  const float* n4g  = (const float*)d_in[7];
  const float* n4b  = (const float*)d_in[8];
  const float* clg  = (const float*)d_in[9];
  const float* clb  = (const float*)d_in[10];
  const float* f1w1 = (const float*)d_in[11];
  const float* f1b1 = (const float*)d_in[12];
  const float* f1w2 = (const float*)d_in[13];
  const float* f1b2 = (const float*)d_in[14];
  const float* f2w1 = (const float*)d_in[15];
  const float* f2b1 = (const float*)d_in[16];
  const float* f2w2 = (const float*)d_in[17];
  const float* f2b2 = (const float*)d_in[18];
  const float* wq   = (const float*)d_in[19];
  const float* bq   = (const float*)d_in[20];
  const float* wk   = (const float*)d_in[21];
  const float* bk   = (const float*)d_in[22];
  const float* wv   = (const float*)d_in[23];
  const float* bv   = (const float*)d_in[24];
  const float* wo   = (const float*)d_in[25];
  const float* bo   = (const float*)d_in[26];
  const float* pw1w = (const float*)d_in[27];
  const float* pw1b = (const float*)d_in[28];
  const float* dww  = (const float*)d_in[29];
  const float* dwb  = (const float*)d_in[30];
  const float* bng  = (const float*)d_in[31];
  const float* bnb  = (const float*)d_in[32];
  const float* bnm  = (const float*)d_in[33];
  const float* bnv  = (const float*)d_in[34];
  const float* pw2w = (const float*)d_in[35];
  const float* pw2b = (const float*)d_in[36];

  char* wsb = (char*)d_ws;
  const size_t MB = 1ull << 20;
  ushort_t* Wbf    = (ushort_t*)(wsb + 0);
  ushort_t* f1w1T  = Wbf + 0;                          // [2048][512]
  ushort_t* f1w2T  = Wbf + (1ull << 20);               // [512][2048]
  ushort_t* f2w1T  = Wbf + (2ull << 20);
  ushort_t* f2w2T  = Wbf + (3ull << 20);
  ushort_t* wqkvT  = Wbf + (4ull << 20);               // [1536][512] (q|k|v)
  ushort_t* wkT    = wqkvT + (256ull << 10);
  ushort_t* wvT    = wqkvT + (512ull << 10);
  ushort_t* woT    = wqkvT + (768ull << 10);
  ushort_t* pw1T   = Wbf + (5ull << 20);               // [1024][512]
  ushort_t* pw2T   = Wbf + (5ull << 20) + (512ull << 10);
  float*    WTc    = (float*)(wsb + 12 * MB);          // dw weight [K][D]
  float*    bcat   = (float*)(wsb + 12 * MB + 128 * 1024);
  ushort_t* Lbf    = (ushort_t*)(wsb + 13 * MB);       // LN out bf16, 8 MB
  ushort_t* Hbf    = (ushort_t*)(wsb + 21 * MB);       // FF hidden / pw1 out (<=32 MB)
  ushort_t* P1bf   = Hbf;
  ushort_t* QKVb   = (ushort_t*)(wsb + 53 * MB);       // [8192][1536] 24 MB
  ushort_t* Vtb    = (ushort_t*)(wsb + 77 * MB);       // 8 MB
  ushort_t* Gbf    = (ushort_t*)(wsb + 53 * MB);       // GLU out (reuses QKV)
  ushort_t* Obf    = (ushort_t*)(wsb + 85 * MB);       // attn out 8 MB
  ushort_t* Cbf    = Obf;                              // conv out (reuses Obf)
  float* out = (float*)d_out;

  const dim3 blk(256);
  const dim3 blkT(32, 8);
  const dim3 gLN(TOK / 4);
  const dim3 gFFa(FDIM / 128, TOK / 128);      // TN=128, N=2048
  const dim3 gFFb(DMODEL / 64, TOK / 128);     // TN=64,  N=512 -> 512 blocks
  const dim3 gQKV(3 * DMODEL / 128, TOK / 128);// TN=128, N=1536 -> 768 blocks
  const dim3 gPW1(2 * DMODEL / 128, TOK / 128);// TN=128, N=1024 -> 512 blocks
  const dim3 gAttn(SEQ / 64, NH, BATCH);
  const dim3 gVt(SEQ / 64, BATCH * NH);
  const dim3 gElem(TOK * 128 / 256);

  // ---- weight preprocessing: ONE wcast dispatch + one misc dispatch ----
  {
    WJobs jobs;
    const float* srcs[10] = {f1w1, f1w2, f2w1, f2w2, wq, wk, wv, wo, pw1w, pw2w};
    ushort_t* dsts[10] = {f1w1T, f1w2T, f2w1T, f2w2T, wqkvT, wkT, wvT, woT, pw1T, pw2T};
    const int Ks[10] = {512, 2048, 512, 2048, 512, 512, 512, 512, 512, 512};
    const int Ns[10] = {2048, 512, 2048, 512, 512, 512, 512, 512, 1024, 512};
    int t0 = 0;
    for (int i = 0; i < 10; ++i) {
      jobs.j[i].src = srcs[i]; jobs.j[i].dst = dsts[i];
      jobs.j[i].K = Ks[i]; jobs.j[i].N = Ns[i]; jobs.j[i].t0 = t0;
      t0 += (Ks[i] / 32) * (Ns[i] / 32);
    }
    wcast_all<<<t0, blkT, 0, stream>>>(jobs);
  }
  misc_prep<<<68, blk, 0, stream>>>(dww, WTc, bq, bk, bv, bcat);

  // ---- FF1 half-step ----
  ln_kernel<true><<<gLN, blk, 0, stream>>>(x, n1g, n1b, Lbf);
  gemm_bf16<128, 1, false, true,  false><<<gFFa, blk, 0, stream>>>(Lbf, f1w1T, f1b1, nullptr, 0.f, Hbf, TOK, FDIM, DMODEL);
  gemm_bf16<64,  0, true,  false, false><<<gFFb, blk, 0, stream>>>(Hbf, f1w2T, f1b2, x, 0.5f, out, TOK, DMODEL, FDIM);

  // ---- MHSA ----
  ln_kernel<true><<<gLN, blk, 0, stream>>>(out, n2g, n2b, Lbf);
  gemm_bf16<128, 0, false, true,  true ><<<gQKV, blk, 0, stream>>>(Lbf, wqkvT, bcat, nullptr, 0.f, QKVb, TOK, 3 * DMODEL, DMODEL);
  vtrans<<<gVt, blk, 0, stream>>>(QKVb, Vtb);
  attn_mfma<<<gAttn, blk, 0, stream>>>(QKVb, Vtb, Obf);
  gemm_bf16<64,  0, true,  false, false><<<gFFb, blk, 0, stream>>>(Obf, woT, bo, out, 1.0f, out, TOK, DMODEL, DMODEL);

  // ---- conv module ----
  ln2_kernel<<<gLN, blk, 0, stream>>>(out, n3g, n3b, clg, clb, Lbf);
  gemm_bf16<128, 0, false, true,  false><<<gPW1, blk, 0, stream>>>(Lbf, pw1T, pw1b, nullptr, 0.f, P1bf, TOK, 2 * DMODEL, DMODEL);
  glu_kernel<<<gElem, blk, 0, stream>>>(P1bf, Gbf);
  dwconv_bn_silu<<<gElem, blk, 0, stream>>>(Gbf, WTc, dwb, bng, bnb, bnm, bnv, Cbf);
  gemm_bf16<64,  0, true,  false, false><<<gFFb, blk, 0, stream>>>(Cbf, pw2T, pw2b, out, 1.0f, out, TOK, DMODEL, DMODEL);

  // ---- FF2 half-step ----
  ln_kernel<true><<<gLN, blk, 0, stream>>>(out, n4g, n4b, Lbf);
  gemm_bf16<128, 1, false, true,  false><<<gFFa, blk, 0, stream>>>(Lbf, f2w1T, f2b1, nullptr, 0.f, Hbf, TOK, FDIM, DMODEL);
  gemm_bf16<64,  0, true,  false, false><<<gFFb, blk, 0, stream>>>(Hbf, f2w2T, f2b2, out, 0.5f, out, TOK, DMODEL, FDIM);
}

// Round 5
// 352.180 us; speedup vs baseline: 4.8536x; 1.0279x over previous
//
#include <hip/hip_runtime.h>
#include <math.h>

#define TOK    8192
#define DMODEL 512
#define FDIM   2048
#define NH     8
#define DKH    64
#define SEQ    1024
#define BATCH  8
#define KCONV  31
#define LN_EPS 1e-5f

typedef __attribute__((ext_vector_type(8))) short bf16x8;
typedef __attribute__((ext_vector_type(4))) float f32x4;
typedef unsigned short ushort_t;

__device__ __forceinline__ float sigf(float x) { return 1.0f / (1.0f + __expf(-x)); }

__device__ __forceinline__ unsigned short f2bf(float f) {
  unsigned u = __float_as_uint(f);
  u = u + 0x7fffu + ((u >> 16) & 1u);   // RNE
  return (unsigned short)(u >> 16);
}
__device__ __forceinline__ unsigned pk2(float a, float b) {
  return (unsigned)f2bf(a) | ((unsigned)f2bf(b) << 16);
}
__device__ __forceinline__ float bf2f(ushort_t u) {
  return __uint_as_float((unsigned)u << 16);
}

// XCD-aware bijective block swizzle (grids here are multiples of 8).
__device__ __forceinline__ void xcd_swizzle(int gx, int* bx, int* by) {
  const int nwg = gx * (int)gridDim.y;
  const int cpx = nwg >> 3;
  const int bid = (*by) * gx + (*bx);
  const int wg = (bid & 7) * cpx + (bid >> 3);
  *bx = wg % gx;
  *by = wg / gx;
}

// ---------------- all-weights cast+transpose in ONE dispatch ----------------
struct WJob { const float* src; ushort_t* dst; int K, N, t0; };
struct WJobs { WJob j[10]; };

__global__ __launch_bounds__(256) void wcast_all(WJobs jobs) {
  __shared__ float tile[32][33];
  const int t = blockIdx.x;
  int i = 0;
#pragma unroll
  for (int k = 1; k < 10; ++k) if (t >= jobs.j[k].t0) i = k;
  const WJob jb = jobs.j[i];
  const int local = t - jb.t0;
  const int ntx = jb.N >> 5;
  const int bx = (local % ntx) * 32, by = (local / ntx) * 32;
  const int tx = threadIdx.x, ty = threadIdx.y;  // 32 x 8
#pragma unroll
  for (int r = 0; r < 32; r += 8)
    tile[ty + r][tx] = jb.src[(size_t)(by + ty + r) * jb.N + bx + tx];
  __syncthreads();
#pragma unroll
  for (int r = 0; r < 32; r += 8)
    jb.dst[(size_t)(bx + ty + r) * jb.K + by + tx] = f2bf(tile[tx][ty + r]);
}

// ---------------- misc prep: dw-weight transpose + qkv bias concat ----------
__global__ void misc_prep(const float* __restrict__ w, float* __restrict__ wT,
                          const float* __restrict__ bq, const float* __restrict__ bk,
                          const float* __restrict__ bv, float* __restrict__ bcat) {
  const int idx = blockIdx.x * 256 + threadIdx.x;
  if (idx < DMODEL * KCONV) {
    const int d = idx / KCONV, k = idx % KCONV;
    wT[k * DMODEL + d] = w[idx];
  } else if (idx < DMODEL * KCONV + 3 * DMODEL) {
    const int c = idx - DMODEL * KCONV;
    bcat[c] = (c < DMODEL) ? bq[c] : (c < 2 * DMODEL ? bk[c - DMODEL] : bv[c - 2 * DMODEL]);
  }
}

// ---------------- LayerNorm: one wave per 512-wide row ----------------------
template <bool OBF>
__global__ __launch_bounds__(256) void ln_kernel(const float* __restrict__ in,
                                                 const float* __restrict__ g,
                                                 const float* __restrict__ b,
                                                 void* __restrict__ outp) {
  const int wave = threadIdx.x >> 6, lane = threadIdx.x & 63;
  const size_t row = (size_t)blockIdx.x * 4 + wave;
  const float* p = in + row * DMODEL + lane * 8;
  const float4 v0 = *(const float4*)p;
  const float4 v1 = *(const float4*)(p + 4);
  float s  = v0.x + v0.y + v0.z + v0.w + v1.x + v1.y + v1.z + v1.w;
  float ss = v0.x*v0.x + v0.y*v0.y + v0.z*v0.z + v0.w*v0.w
           + v1.x*v1.x + v1.y*v1.y + v1.z*v1.z + v1.w*v1.w;
#pragma unroll
  for (int m = 1; m < 64; m <<= 1) { s += __shfl_xor(s, m); ss += __shfl_xor(ss, m); }
  const float mean = s * (1.0f / DMODEL);
  const float var  = ss * (1.0f / DMODEL) - mean * mean;
  const float rstd = rsqrtf(var + LN_EPS);
  const float4 g0 = *(const float4*)(g + lane * 8);
  const float4 g1 = *(const float4*)(g + lane * 8 + 4);
  const float4 bb0 = *(const float4*)(b + lane * 8);
  const float4 bb1 = *(const float4*)(b + lane * 8 + 4);
  float o[8];
  o[0] = (v0.x - mean) * rstd * g0.x + bb0.x;
  o[1] = (v0.y - mean) * rstd * g0.y + bb0.y;
  o[2] = (v0.z - mean) * rstd * g0.z + bb0.z;
  o[3] = (v0.w - mean) * rstd * g0.w + bb0.w;
  o[4] = (v1.x - mean) * rstd * g1.x + bb1.x;
  o[5] = (v1.y - mean) * rstd * g1.y + bb1.y;
  o[6] = (v1.z - mean) * rstd * g1.z + bb1.z;
  o[7] = (v1.w - mean) * rstd * g1.w + bb1.w;
  if (OBF) {
    uint4 pkv;
    pkv.x = pk2(o[0], o[1]); pkv.y = pk2(o[2], o[3]);
    pkv.z = pk2(o[4], o[5]); pkv.w = pk2(o[6], o[7]);
    *(uint4*)((ushort_t*)outp + row * DMODEL + lane * 8) = pkv;
  } else {
    float4 a, c;
    a.x = o[0]; a.y = o[1]; a.z = o[2]; a.w = o[3];
    c.x = o[4]; c.y = o[5]; c.z = o[6]; c.w = o[7];
    float* q = (float*)outp + row * DMODEL + lane * 8;
    *(float4*)q = a;
    *(float4*)(q + 4) = c;
  }
}

// ---------------- fused double LayerNorm (norm3 then conv_ln), bf16 out -----
__global__ __launch_bounds__(256) void ln2_kernel(const float* __restrict__ in,
                                                  const float* __restrict__ g1,
                                                  const float* __restrict__ b1,
                                                  const float* __restrict__ g2,
                                                  const float* __restrict__ b2,
                                                  ushort_t* __restrict__ outp) {
  const int wave = threadIdx.x >> 6, lane = threadIdx.x & 63;
  const size_t row = (size_t)blockIdx.x * 4 + wave;
  const float* p = in + row * DMODEL + lane * 8;
  float v[8];
  {
    const float4 v0 = *(const float4*)p;
    const float4 v1 = *(const float4*)(p + 4);
    v[0]=v0.x; v[1]=v0.y; v[2]=v0.z; v[3]=v0.w;
    v[4]=v1.x; v[5]=v1.y; v[6]=v1.z; v[7]=v1.w;
  }
  float s = 0.f, ss = 0.f;
#pragma unroll
  for (int e = 0; e < 8; ++e) { s += v[e]; ss += v[e]*v[e]; }
#pragma unroll
  for (int m = 1; m < 64; m <<= 1) { s += __shfl_xor(s, m); ss += __shfl_xor(ss, m); }
  float mean = s * (1.0f / DMODEL);
  float rstd = rsqrtf(ss * (1.0f / DMODEL) - mean * mean + LN_EPS);
  const float4 ga = *(const float4*)(g1 + lane * 8);
  const float4 gb = *(const float4*)(g1 + lane * 8 + 4);
  const float4 ba = *(const float4*)(b1 + lane * 8);
  const float4 bb = *(const float4*)(b1 + lane * 8 + 4);
  const float gg1[8] = {ga.x,ga.y,ga.z,ga.w,gb.x,gb.y,gb.z,gb.w};
  const float bb1[8] = {ba.x,ba.y,ba.z,ba.w,bb.x,bb.y,bb.z,bb.w};
#pragma unroll
  for (int e = 0; e < 8; ++e) v[e] = (v[e] - mean) * rstd * gg1[e] + bb1[e];
  s = 0.f; ss = 0.f;
#pragma unroll
  for (int e = 0; e < 8; ++e) { s += v[e]; ss += v[e]*v[e]; }
#pragma unroll
  for (int m = 1; m < 64; m <<= 1) { s += __shfl_xor(s, m); ss += __shfl_xor(ss, m); }
  mean = s * (1.0f / DMODEL);
  rstd = rsqrtf(ss * (1.0f / DMODEL) - mean * mean + LN_EPS);
  const float4 gc = *(const float4*)(g2 + lane * 8);
  const float4 gd = *(const float4*)(g2 + lane * 8 + 4);
  const float4 bc = *(const float4*)(b2 + lane * 8);
  const float4 bd = *(const float4*)(b2 + lane * 8 + 4);
  const float gg2[8] = {gc.x,gc.y,gc.z,gc.w,gd.x,gd.y,gd.z,gd.w};
  const float bb2[8] = {bc.x,bc.y,bc.z,bc.w,bd.x,bd.y,bd.z,bd.w};
  float o[8];
#pragma unroll
  for (int e = 0; e < 8; ++e) o[e] = (v[e] - mean) * rstd * gg2[e] + bb2[e];
  uint4 pkv;
  pkv.x = pk2(o[0], o[1]); pkv.y = pk2(o[2], o[3]);
  pkv.z = pk2(o[4], o[5]); pkv.w = pk2(o[6], o[7]);
  *(uint4*)(outp + row * DMODEL + lane * 8) = pkv;
}

// ---------------- bf16 MFMA GEMM (m97 structure), TN = 128 or 64 ------------
// A [M,K] bf16; Bt [N,K] bf16. C = act(A@B + bias); QSC: cols<512 scaled 1/8.
// RES: C = Rp + alpha*C. OBF: bf16 out. 128xTN tile, BK=64, 4 waves (2x2).
template <int TN, int ACT, bool RES, bool OBF, bool QSC>
__global__ __launch_bounds__(256) void gemm_bf16(const ushort_t* __restrict__ A,
                                                 const ushort_t* __restrict__ Bt,
                                                 const float* __restrict__ bias,
                                                 const float* __restrict__ Rp,
                                                 float alpha,
                                                 void* __restrict__ Cout,
                                                 int M, int N, int K) {
  constexpr int NF = TN / 32;
  constexpr int NB = TN / 32;
  __shared__ ushort_t Al[128 * 64];
  __shared__ ushort_t Bl[TN * 64];
  const int t = threadIdx.x;
  const int lane = t & 63;
  const int wid = t >> 6;
  const int wr = wid >> 1, wc = wid & 1;
  int bx = blockIdx.x, by = blockIdx.y;
  xcd_swizzle(gridDim.x, &bx, &by);
  const int m0 = by * 128, n0 = bx * TN;

  f32x4 acc[4][NF];
#pragma unroll
  for (int m = 0; m < 4; ++m)
#pragma unroll
    for (int n = 0; n < NF; ++n) acc[m][n] = (f32x4){0.f, 0.f, 0.f, 0.f};

  const int srow = t >> 3;
  const int scol = (t & 7) * 8;
  const ushort_t* Ag = A + (size_t)(m0 + srow) * K + scol;
  const ushort_t* Bg = Bt + (size_t)(n0 + srow) * K + scol;

  for (int k0 = 0; k0 < K; k0 += 64) {
    __syncthreads();
#pragma unroll
    for (int i = 0; i < 4; ++i) {
      __builtin_amdgcn_global_load_lds(
          (const __attribute__((address_space(1))) unsigned*)(Ag + (size_t)i * 32 * K + k0),
          (__attribute__((address_space(3))) unsigned*)(Al + ((size_t)i * 256 + t) * 8),
          16, 0, 0);
    }
#pragma unroll
    for (int i = 0; i < NB; ++i) {
      __builtin_amdgcn_global_load_lds(
          (const __attribute__((address_space(1))) unsigned*)(Bg + (size_t)i * 32 * K + k0),
          (__attribute__((address_space(3))) unsigned*)(Bl + ((size_t)i * 256 + t) * 8),
          16, 0, 0);
    }
    __syncthreads();

#pragma unroll
    for (int ks = 0; ks < 2; ++ks) {
      const int kk = ks * 32 + (lane >> 4) * 8;
      bf16x8 af[4], bfv[NF];
#pragma unroll
      for (int m = 0; m < 4; ++m)
        af[m] = *(const bf16x8*)(Al + (wr * 64 + m * 16 + (lane & 15)) * 64 + kk);
#pragma unroll
      for (int n = 0; n < NF; ++n)
        bfv[n] = *(const bf16x8*)(Bl + (wc * (TN / 2) + n * 16 + (lane & 15)) * 64 + kk);
#pragma unroll
      for (int m = 0; m < 4; ++m)
#pragma unroll
        for (int n = 0; n < NF; ++n)
          acc[m][n] = __builtin_amdgcn_mfma_f32_16x16x32_bf16(af[m], bfv[n], acc[m][n], 0, 0, 0);
    }
  }

#pragma unroll
  for (int m = 0; m < 4; ++m) {
    const int row_b = m0 + wr * 64 + m * 16 + (lane >> 4) * 4;
#pragma unroll
    for (int n = 0; n < NF; ++n) {
      const int col = n0 + wc * (TN / 2) + n * 16 + (lane & 15);
      const float bv = bias[col];
#pragma unroll
      for (int j = 0; j < 4; ++j) {
        float v = acc[m][n][j] + bv;
        if (ACT == 1) v = fmaxf(v, 0.f);
        if (QSC) v *= (col < DMODEL ? 0.125f : 1.0f);
        const size_t idx = (size_t)(row_b + j) * N + col;
        if (RES) v = Rp[idx] + alpha * v;
        if (OBF) ((ushort_t*)Cout)[idx] = f2bf(v);
        else     ((float*)Cout)[idx] = v;
      }
    }
  }
}

// ---------------- fused pw1 + GLU GEMM --------------------------------------
// A [8192][512] bf16; Bt = pw1T [1024][512] (rows 0..511 = a-half cols,
// rows 512..1023 = g-half). out[row][col] = (A@Wa+ba) * sig(A@Wg+bg), bf16.
__global__ __launch_bounds__(256) void gemm_glu(const ushort_t* __restrict__ A,
                                                const ushort_t* __restrict__ Bt,
                                                const float* __restrict__ bias,
                                                ushort_t* __restrict__ Cout) {
  __shared__ ushort_t Al[128 * 64];
  __shared__ ushort_t Bl[128 * 64];   // rows 0..63 a-cols, 64..127 g-cols
  const int t = threadIdx.x;
  const int lane = t & 63;
  const int wid = t >> 6;
  const int wr = wid >> 1, wc = wid & 1;
  int bx = blockIdx.x, by = blockIdx.y;
  xcd_swizzle(gridDim.x, &bx, &by);
  const int m0 = by * 128, n0 = bx * 64;
  const int K = DMODEL, N = DMODEL;

  f32x4 aa[4][2], ag[4][2];
#pragma unroll
  for (int m = 0; m < 4; ++m)
#pragma unroll
    for (int n = 0; n < 2; ++n) {
      aa[m][n] = (f32x4){0.f, 0.f, 0.f, 0.f};
      ag[m][n] = (f32x4){0.f, 0.f, 0.f, 0.f};
    }

  const int srow = t >> 3;
  const int scol = (t & 7) * 8;
  const ushort_t* Ag_ = A + (size_t)(m0 + srow) * K + scol;
  const ushort_t* Ba_ = Bt + (size_t)(n0 + srow) * K + scol;          // a rows
  const ushort_t* Bg_ = Bt + (size_t)(512 + n0 + srow) * K + scol;    // g rows

  for (int k0 = 0; k0 < K; k0 += 64) {
    __syncthreads();
#pragma unroll
    for (int i = 0; i < 4; ++i) {
      __builtin_amdgcn_global_load_lds(
          (const __attribute__((address_space(1))) unsigned*)(Ag_ + (size_t)i * 32 * K + k0),
          (__attribute__((address_space(3))) unsigned*)(Al + ((size_t)i * 256 + t) * 8),
          16, 0, 0);
    }
#pragma unroll
    for (int i = 0; i < 2; ++i) {
      __builtin_amdgcn_global_load_lds(
          (const __attribute__((address_space(1))) unsigned*)(Ba_ + (size_t)i * 32 * K + k0),
          (__attribute__((address_space(3))) unsigned*)(Bl + ((size_t)i * 256 + t) * 8),
          16, 0, 0);
      __builtin_amdgcn_global_load_lds(
          (const __attribute__((address_space(1))) unsigned*)(Bg_ + (size_t)i * 32 * K + k0),
          (__attribute__((address_space(3))) unsigned*)(Bl + 64 * 64 + ((size_t)i * 256 + t) * 8),
          16, 0, 0);
    }
    __syncthreads();

#pragma unroll
    for (int ks = 0; ks < 2; ++ks) {
      const int kk = ks * 32 + (lane >> 4) * 8;
      bf16x8 af[4], bfa[2], bfg[2];
#pragma unroll
      for (int m = 0; m < 4; ++m)
        af[m] = *(const bf16x8*)(Al + (wr * 64 + m * 16 + (lane & 15)) * 64 + kk);
#pragma unroll
      for (int n = 0; n < 2; ++n) {
        bfa[n] = *(const bf16x8*)(Bl + (wc * 32 + n * 16 + (lane & 15)) * 64 + kk);
        bfg[n] = *(const bf16x8*)(Bl + (64 + wc * 32 + n * 16 + (lane & 15)) * 64 + kk);
      }
#pragma unroll
      for (int m = 0; m < 4; ++m)
#pragma unroll
        for (int n = 0; n < 2; ++n) {
          aa[m][n] = __builtin_amdgcn_mfma_f32_16x16x32_bf16(af[m], bfa[n], aa[m][n], 0, 0, 0);
          ag[m][n] = __builtin_amdgcn_mfma_f32_16x16x32_bf16(af[m], bfg[n], ag[m][n], 0, 0, 0);
        }
    }
  }

#pragma unroll
  for (int m = 0; m < 4; ++m) {
    const int row_b = m0 + wr * 64 + m * 16 + (lane >> 4) * 4;
#pragma unroll
    for (int n = 0; n < 2; ++n) {
      const int col = n0 + wc * 32 + n * 16 + (lane & 15);
      const float ba_v = bias[col];
      const float bg_v = bias[col + DMODEL];
#pragma unroll
      for (int j = 0; j < 4; ++j) {
        const float av = aa[m][n][j] + ba_v;
        const float gv = ag[m][n][j] + bg_v;
        Cout[(size_t)(row_b + j) * N + col] = f2bf(av * sigf(gv));
      }
    }
  }
}

// ---------------- V transpose per head: QKV[b][s][1024+h*64+d] -> [bh][d][s] -
__global__ __launch_bounds__(256) void vtrans(const ushort_t* __restrict__ QKV,
                                              ushort_t* __restrict__ Vt) {
  __shared__ ushort_t tl[64][72];
  const int st = blockIdx.x;
  const int bh = blockIdx.y;
  const int b = bh >> 3, h = bh & 7;
  const int t = threadIdx.x;
#pragma unroll
  for (int i = 0; i < 2; ++i) {
    const int chunk = i * 256 + t;
    const int sr = chunk >> 3, c8 = (chunk & 7) * 8;
    *(uint4*)&tl[sr][c8] =
        *(const uint4*)(QKV + ((size_t)(b * SEQ + st * 64 + sr) * (3 * DMODEL)) + 2 * DMODEL + h * DKH + c8);
  }
  __syncthreads();
#pragma unroll
  for (int i = 0; i < 2; ++i) {
    const int chunk = i * 256 + t;
    const int dr = chunk >> 3, c8 = (chunk & 7) * 8;
    ushort_t tmp[8];
#pragma unroll
    for (int e = 0; e < 8; ++e) tmp[e] = tl[c8 + e][dr];
    *(uint4*)(Vt + ((size_t)(bh * DKH + dr) * SEQ) + st * 64 + c8) = *(uint4*)tmp;
  }
}

// ---------------- MFMA flash attention, QBLK=128, KVBLK=128, 8 waves --------
// grid (S/128, H, B), 512 thr. Q pre-scaled by 1/8 in QKV epilogue.
__global__ __launch_bounds__(512) void attn_mfma(const ushort_t* __restrict__ QKV,
                                                 const ushort_t* __restrict__ Vt,
                                                 ushort_t* __restrict__ Om) {
  __shared__ ushort_t Ks[128 * 64];   // [key][dk]  rows 128 B, swizzled
  __shared__ ushort_t Vs[64 * 128];   // [dk][key]  rows 256 B, swizzled
  __shared__ ushort_t Ps[128 * 128];  // [q][key]   rows 256 B, swizzled
  const int t = threadIdx.x;
  const int l = t & 63;
  const int w = t >> 6;               // 0..7
  const int qb = blockIdx.x, h = blockIdx.y, b = blockIdx.z;
  const size_t rowstr = 3 * DMODEL;
  const size_t baseQ = ((size_t)b * SEQ) * rowstr + (size_t)h * DKH;
  const size_t baseK = baseQ + DMODEL;
  const size_t baseV = (size_t)(b * NH + h) * DKH * SEQ;
  const size_t baseO = ((size_t)b * SEQ) * DMODEL + (size_t)h * DKH;

  bf16x8 qf[2];
  {
    const int qrow = qb * 128 + w * 16 + (l & 15);
    const ushort_t* qp = QKV + baseQ + (size_t)qrow * rowstr + ((l >> 4) * 8);
    qf[0] = *(const bf16x8*)(qp);
    qf[1] = *(const bf16x8*)(qp + 32);
  }

  float mrun[4], lrun[4];
  f32x4 o[4];
#pragma unroll
  for (int j = 0; j < 4; ++j) { mrun[j] = -1e30f; lrun[j] = 0.f; }
#pragma unroll
  for (int n = 0; n < 4; ++n) o[n] = (f32x4){0.f, 0.f, 0.f, 0.f};

  for (int kt = 0; kt < SEQ / 128; ++kt) {
    __syncthreads();
    // stage K [128][64] and V^T [64][128], swizzled
#pragma unroll
    for (int i = 0; i < 2; ++i) {
      const int chunk = i * 512 + t;
      {
        const int r = chunk >> 3, c8 = (chunk & 7) * 8;
        const uint4 kv = *(const uint4*)(QKV + baseK + (size_t)(kt * 128 + r) * rowstr + c8);
        *(uint4*)((char*)Ks + r * 128 + ((c8 * 2) ^ ((r & 7) << 4))) = kv;
      }
      {
        const int r = chunk >> 4, c8 = (chunk & 15) * 8;
        const uint4 vv = *(const uint4*)(Vt + baseV + (size_t)r * SEQ + kt * 128 + c8);
        *(uint4*)((char*)Vs + r * 256 + ((c8 * 2) ^ ((r & 15) << 4))) = vv;
      }
    }
    __syncthreads();

    // S = Q K^T : 16 q-rows x 128 keys per wave
    f32x4 s[8];
#pragma unroll
    for (int n = 0; n < 8; ++n) s[n] = (f32x4){0.f, 0.f, 0.f, 0.f};
#pragma unroll
    for (int ks = 0; ks < 2; ++ks) {
      const int kk = ks * 64 + (l >> 4) * 16;
#pragma unroll
      for (int n = 0; n < 8; ++n) {
        const int krow = n * 16 + (l & 15);
        const bf16x8 kf = *(const bf16x8*)((char*)Ks + krow * 128 + (kk ^ ((krow & 7) << 4)));
        s[n] = __builtin_amdgcn_mfma_f32_16x16x32_bf16(qf[ks], kf, s[n], 0, 0, 0);
      }
    }

    // online softmax; P -> bf16 via swizzled LDS (wave-local rows)
#pragma unroll
    for (int j = 0; j < 4; ++j) {
      float r0 = s[0][j];
#pragma unroll
      for (int n = 1; n < 8; ++n) r0 = fmaxf(r0, s[n][j]);
      r0 = fmaxf(r0, __shfl_xor(r0, 1));
      r0 = fmaxf(r0, __shfl_xor(r0, 2));
      r0 = fmaxf(r0, __shfl_xor(r0, 4));
      r0 = fmaxf(r0, __shfl_xor(r0, 8));
      const float mn = fmaxf(mrun[j], r0);
      const float cs = __expf(mrun[j] - mn);
      const int prow = w * 16 + (l >> 4) * 4 + j;
      const int pswz = (prow & 15) << 4;
      float psum = 0.f;
#pragma unroll
      for (int n = 0; n < 8; ++n) {
        const float p = __expf(s[n][j] - mn);
        psum += p;
        const int col2 = (n * 16 + (l & 15)) * 2;
        *(ushort_t*)((char*)Ps + prow * 256 + (col2 ^ pswz)) = f2bf(p);
      }
      psum += __shfl_xor(psum, 1);
      psum += __shfl_xor(psum, 2);
      psum += __shfl_xor(psum, 4);
      psum += __shfl_xor(psum, 8);
      lrun[j] = lrun[j] * cs + psum;
      mrun[j] = mn;
      o[0][j] *= cs; o[1][j] *= cs; o[2][j] *= cs; o[3][j] *= cs;
    }

    // O += P V
#pragma unroll
    for (int ks = 0; ks < 4; ++ks) {
      const int kk = ks * 64 + (l >> 4) * 16;
      const int arow = w * 16 + (l & 15);
      const bf16x8 pf = *(const bf16x8*)((char*)Ps + arow * 256 + (kk ^ ((arow & 15) << 4)));
#pragma unroll
      for (int n = 0; n < 4; ++n) {
        const int vrow = n * 16 + (l & 15);
        const bf16x8 vf = *(const bf16x8*)((char*)Vs + vrow * 256 + (kk ^ ((vrow & 15) << 4)));
        o[n] = __builtin_amdgcn_mfma_f32_16x16x32_bf16(pf, vf, o[n], 0, 0, 0);
      }
    }
  }

  // normalize, repack through LDS, coalesced bf16 store
  float inv[4];
#pragma unroll
  for (int j = 0; j < 4; ++j) inv[j] = 1.0f / lrun[j];
#pragma unroll
  for (int j = 0; j < 4; ++j) {
    const int prow = w * 16 + (l >> 4) * 4 + j;
    const int pswz = (prow & 15) << 4;
#pragma unroll
    for (int n = 0; n < 4; ++n) {
      const int col2 = (n * 16 + (l & 15)) * 2;
      *(ushort_t*)((char*)Ps + prow * 256 + (col2 ^ pswz)) = f2bf(o[n][j] * inv[j]);
    }
  }
  __syncthreads();
#pragma unroll
  for (int i = 0; i < 2; ++i) {
    const int chunk = i * 512 + t;
    const int qr = chunk >> 3, c8 = (chunk & 7) * 8;
    const uint4 ov = *(const uint4*)((char*)Ps + qr * 256 + ((c8 * 2) ^ ((qr & 15) << 4)));
    *(uint4*)(Om + baseO + (size_t)(qb * 128 + qr) * DMODEL + c8) = ov;
  }
}

// ---------------- depthwise conv + bias + BN + SiLU, bf16 in/out ------------
__global__ __launch_bounds__(256) void dwconv_bn_silu(const ushort_t* __restrict__ in,
                                                      const float* __restrict__ wT,
                                                      const float* __restrict__ dwb,
                                                      const float* __restrict__ bng,
                                                      const float* __restrict__ bnb,
                                                      const float* __restrict__ bnm,
                                                      const float* __restrict__ bnv,
                                                      ushort_t* __restrict__ out) {
  const size_t gid = (size_t)blockIdx.x * 256 + threadIdx.x;
  const int dc = (int)(gid & 127) * 4;
  const int s = (int)((gid >> 7) & (SEQ - 1));
  const int b = (int)(gid >> 17);
  const ushort_t* bp = in + (size_t)b * SEQ * DMODEL;
  float ax = 0.f, ay = 0.f, az = 0.f, aw = 0.f;
#pragma unroll
  for (int k = 0; k < KCONV; ++k) {
    const int ssi = s + k - (KCONV / 2);
    if (ssi < 0 || ssi >= SEQ) continue;
    ushort_t xv[4];
    *(uint2*)xv = *(const uint2*)(bp + (size_t)ssi * DMODEL + dc);
    const float4 w = *(const float4*)(wT + k * DMODEL + dc);
    ax = fmaf(bf2f(xv[0]), w.x, ax); ay = fmaf(bf2f(xv[1]), w.y, ay);
    az = fmaf(bf2f(xv[2]), w.z, az); aw = fmaf(bf2f(xv[3]), w.w, aw);
  }
  const float4 bi = *(const float4*)(dwb + dc);
  const float4 mm = *(const float4*)(bnm + dc);
  const float4 vv = *(const float4*)(bnv + dc);
  const float4 gg = *(const float4*)(bng + dc);
  const float4 b2 = *(const float4*)(bnb + dc);
  float v0 = ax + bi.x, v1 = ay + bi.y, v2 = az + bi.z, v3 = aw + bi.w;
  v0 = (v0 - mm.x) * rsqrtf(vv.x + LN_EPS) * gg.x + b2.x;
  v1 = (v1 - mm.y) * rsqrtf(vv.y + LN_EPS) * gg.y + b2.y;
  v2 = (v2 - mm.z) * rsqrtf(vv.z + LN_EPS) * gg.z + b2.z;
  v3 = (v3 - mm.w) * rsqrtf(vv.w + LN_EPS) * gg.w + b2.w;
  v0 = v0 * sigf(v0); v1 = v1 * sigf(v1); v2 = v2 * sigf(v2); v3 = v3 * sigf(v3);
  uint2 o;
  o.x = pk2(v0, v1); o.y = pk2(v2, v3);
  *(uint2*)&out[(((size_t)b * SEQ + s) * DMODEL) + dc] = o;
}

extern "C" void kernel_launch(void* const* d_in, const int* in_sizes, int n_in,
                              void* d_out, int out_size, void* d_ws, size_t ws_size,
                              hipStream_t stream) {
  const float* x    = (const float*)d_in[0];
  const float* n1g  = (const float*)d_in[1];
  const float* n1b  = (const float*)d_in[2];
  const float* n2g  = (const float*)d_in[3];
  const float* n2b  = (const float*)d_in[4];
  const float* n3g  = (const float*)d_in[5];
  const float* n3b  = (const float*)d_in[6];
  const float* n4g  = (const float*)d_in[7];
  const float* n4b  = (const float*)d_in[8];
  const float* clg  = (const float*)d_in[9];
  const float* clb  = (const float*)d_in[10];
  const float* f1w1 = (const float*)d_in[11];
  const float* f1b1 = (const float*)d_in[12];
  const float* f1w2 = (const float*)d_in[13];
  const float* f1b2 = (const float*)d_in[14];
  const float* f2w1 = (const float*)d_in[15];
  const float* f2b1 = (const float*)d_in[16];
  const float* f2w2 = (const float*)d_in[17];
  const float* f2b2 = (const float*)d_in[18];
  const float* wq   = (const float*)d_in[19];
  const float* bq   = (const float*)d_in[20];
  const float* wk   = (const float*)d_in[21];
  const float* bk   = (const float*)d_in[22];
  const float* wv   = (const float*)d_in[23];
  const float* bv   = (const float*)d_in[24];
  const float* wo   = (const float*)d_in[25];
  const float* bo   = (const float*)d_in[26];
  const float* pw1w = (const float*)d_in[27];
  const float* pw1b = (const float*)d_in[28];
  const float* dww  = (const float*)d_in[29];
  const float* dwb  = (const float*)d_in[30];
  const float* bng  = (const float*)d_in[31];
  const float* bnb  = (const float*)d_in[32];
  const float* bnm  = (const float*)d_in[33];
  const float* bnv  = (const float*)d_in[34];
  const float* pw2w = (const float*)d_in[35];
  const float* pw2b = (const float*)d_in[36];

  char* wsb = (char*)d_ws;
  const size_t MB = 1ull << 20;
  ushort_t* Wbf    = (ushort_t*)(wsb + 0);
  ushort_t* f1w1T  = Wbf + 0;                          // [2048][512]
  ushort_t* f1w2T  = Wbf + (1ull << 20);               // [512][2048]
  ushort_t* f2w1T  = Wbf + (2ull << 20);
  ushort_t* f2w2T  = Wbf + (3ull << 20);
  ushort_t* wqkvT  = Wbf + (4ull << 20);               // [1536][512] (q|k|v)
  ushort_t* wkT    = wqkvT + (256ull << 10);
  ushort_t* wvT    = wqkvT + (512ull << 10);
  ushort_t* woT    = wqkvT + (768ull << 10);
  ushort_t* pw1T   = Wbf + (5ull << 20);               // [1024][512]
  ushort_t* pw2T   = Wbf + (5ull << 20) + (512ull << 10);
  float*    WTc    = (float*)(wsb + 12 * MB);          // dw weight [K][D]
  float*    bcat   = (float*)(wsb + 12 * MB + 128 * 1024);
  ushort_t* Lbf    = (ushort_t*)(wsb + 13 * MB);       // LN out bf16, 8 MB
  ushort_t* Hbf    = (ushort_t*)(wsb + 21 * MB);       // FF hidden (32 MB)
  ushort_t* QKVb   = (ushort_t*)(wsb + 53 * MB);       // [8192][1536] 24 MB
  ushort_t* Vtb    = (ushort_t*)(wsb + 77 * MB);       // 8 MB
  ushort_t* Gbf    = (ushort_t*)(wsb + 53 * MB);       // GLU out (reuses QKV)
  ushort_t* Obf    = (ushort_t*)(wsb + 85 * MB);       // attn out 8 MB
  ushort_t* Cbf    = Obf;                              // conv out (reuses Obf)
  float* out = (float*)d_out;

  const dim3 blk(256);
  const dim3 blk512(512);
  const dim3 blkT(32, 8);
  const dim3 gLN(TOK / 4);
  const dim3 gFFa(FDIM / 128, TOK / 128);       // 1024 blocks
  const dim3 gFFb(DMODEL / 64, TOK / 128);      // 512 blocks
  const dim3 gQKV(3 * DMODEL / 128, TOK / 128); // 768 blocks
  const dim3 gGLU(DMODEL / 64, TOK / 128);      // 512 blocks
  const dim3 gAttn(SEQ / 128, NH, BATCH);       // 512 blocks
  const dim3 gVt(SEQ / 64, BATCH * NH);
  const dim3 gElem(TOK * 128 / 256);

  // ---- weight preprocessing ----
  {
    WJobs jobs;
    const float* srcs[10] = {f1w1, f1w2, f2w1, f2w2, wq, wk, wv, wo, pw1w, pw2w};
    ushort_t* dsts[10] = {f1w1T, f1w2T, f2w1T, f2w2T, wqkvT, wkT, wvT, woT, pw1T, pw2T};
    const int Ks[10] = {512, 2048, 512, 2048, 512, 512, 512, 512, 512, 512};
    const int Ns[10] = {2048, 512, 2048, 512, 512, 512, 512, 512, 1024, 512};
    int t0 = 0;
    for (int i = 0; i < 10; ++i) {
      jobs.j[i].src = srcs[i]; jobs.j[i].dst = dsts[i];
      jobs.j[i].K = Ks[i]; jobs.j[i].N = Ns[i]; jobs.j[i].t0 = t0;
      t0 += (Ks[i] / 32) * (Ns[i] / 32);
    }
    wcast_all<<<t0, blkT, 0, stream>>>(jobs);
  }
  misc_prep<<<68, blk, 0, stream>>>(dww, WTc, bq, bk, bv, bcat);

  // ---- FF1 half-step ----
  ln_kernel<true><<<gLN, blk, 0, stream>>>(x, n1g, n1b, Lbf);
  gemm_bf16<128, 1, false, true,  false><<<gFFa, blk, 0, stream>>>(Lbf, f1w1T, f1b1, nullptr, 0.f, Hbf, TOK, FDIM, DMODEL);
  gemm_bf16<64,  0, true,  false, false><<<gFFb, blk, 0, stream>>>(Hbf, f1w2T, f1b2, x, 0.5f, out, TOK, DMODEL, FDIM);

  // ---- MHSA ----
  ln_kernel<true><<<gLN, blk, 0, stream>>>(out, n2g, n2b, Lbf);
  gemm_bf16<128, 0, false, true,  true ><<<gQKV, blk, 0, stream>>>(Lbf, wqkvT, bcat, nullptr, 0.f, QKVb, TOK, 3 * DMODEL, DMODEL);
  vtrans<<<gVt, blk, 0, stream>>>(QKVb, Vtb);
  attn_mfma<<<gAttn, blk512, 0, stream>>>(QKVb, Vtb, Obf);
  gemm_bf16<64,  0, true,  false, false><<<gFFb, blk, 0, stream>>>(Obf, woT, bo, out, 1.0f, out, TOK, DMODEL, DMODEL);

  // ---- conv module ----
  ln2_kernel<<<gLN, blk, 0, stream>>>(out, n3g, n3b, clg, clb, Lbf);
  gemm_glu<<<gGLU, blk, 0, stream>>>(Lbf, pw1T, pw1b, Gbf);
  dwconv_bn_silu<<<gElem, blk, 0, stream>>>(Gbf, WTc, dwb, bng, bnb, bnm, bnv, Cbf);
  gemm_bf16<64,  0, true,  false, false><<<gFFb, blk, 0, stream>>>(Cbf, pw2T, pw2b, out, 1.0f, out, TOK, DMODEL, DMODEL);

  // ---- FF2 half-step ----
  ln_kernel<true><<<gLN, blk, 0, stream>>>(out, n4g, n4b, Lbf);
  gemm_bf16<128, 1, false, true,  false><<<gFFa, blk, 0, stream>>>(Lbf, f2w1T, f2b1, nullptr, 0.f, Hbf, TOK, FDIM, DMODEL);
  gemm_bf16<64,  0, true,  false, false><<<gFFb, blk, 0, stream>>>(Hbf, f2w2T, f2b2, out, 0.5f, out, TOK, DMODEL, FDIM);
}